// Round 1
// baseline (26121.381 us; speedup 1.0000x reference)
//
#include <hip/hip_runtime.h>
#include <hip/hip_bf16.h>
#include <math.h>

#define DEV __device__ __forceinline__

DEV float gelu_f(float x) { return 0.5f * x * (1.0f + erff(x * 0.70710678118654752f)); }

// ---------------- zero stats region ----------------
__global__ void k_zero(float* p, int n) {
  int i = blockIdx.x * blockDim.x + threadIdx.x;
  if (i < n) p[i] = 0.f;
}

// ---------------- conv1: x[1024,4,144,160] * w[32,4,8,8] s4 -> y[1024,32,35,39]
__global__ __launch_bounds__(256) void k_conv1(const float* __restrict__ x,
    const float* __restrict__ w, const float* __restrict__ bias, float* __restrict__ y)
{
  __shared__ float ins[10240 + 16];   // [c:4][r:16][col:160]
  __shared__ float ws_[8192];         // [oc:32][c:4][kh:8][kw:8]
  int b = blockIdx.y, oh0 = blockIdx.x * 3, tid = threadIdx.x;
  for (int i = tid; i < 8192; i += 256) ws_[i] = w[i];
  for (int i = tid; i < 10240; i += 256) {
    int c = i / 2560, rr = (i % 2560) / 160, col = i % 160;
    int row = oh0 * 4 + rr;
    ins[i] = (row < 144) ? x[(((long)b * 4 + c) * 144 + row) * 160 + col] : 0.f;
  }
  __syncthreads();
  int t = tid;
  if (t >= 240) return;
  int ocg = t / 30, rem = t % 30, ohl = rem / 10, owg = rem % 10;
  int oh = oh0 + ohl;
  if (oh >= 35) return;
  int oc0 = ocg * 4, ow0 = owg * 4;
  float acc[4][4] = {};
  for (int c = 0; c < 4; ++c)
    for (int kh = 0; kh < 8; ++kh) {
      const float* ip = &ins[c * 2560 + (ohl * 4 + kh) * 160 + ow0 * 4];
      const float* wp = &ws_[oc0 * 256 + c * 64 + kh * 8];
#pragma unroll
      for (int kw = 0; kw < 8; ++kw) {
        float w0 = wp[kw], w1 = wp[kw + 256], w2 = wp[kw + 512], w3 = wp[kw + 768];
        float i0 = ip[kw], i1 = ip[kw + 4], i2 = ip[kw + 8], i3 = ip[kw + 12];
        acc[0][0] += w0 * i0; acc[0][1] += w0 * i1; acc[0][2] += w0 * i2; acc[0][3] += w0 * i3;
        acc[1][0] += w1 * i0; acc[1][1] += w1 * i1; acc[1][2] += w1 * i2; acc[1][3] += w1 * i3;
        acc[2][0] += w2 * i0; acc[2][1] += w2 * i1; acc[2][2] += w2 * i2; acc[2][3] += w2 * i3;
        acc[3][0] += w3 * i0; acc[3][1] += w3 * i1; acc[3][2] += w3 * i2; acc[3][3] += w3 * i3;
      }
    }
  for (int i = 0; i < 4; ++i) {
    float bv = bias[oc0 + i];
    for (int j = 0; j < 4; ++j) {
      int ow = ow0 + j;
      if (ow < 39)
        y[(((long)b * 32 + oc0 + i) * 35 + oh) * 39 + ow] = acc[i][j] + bv;
    }
  }
}

// ---------------- BN stats (sum, sumsq per channel) ----------------
__global__ __launch_bounds__(256) void k_bn_stats(const float* __restrict__ y,
    float* __restrict__ sums, int C, int HW, int Bper)
{
  int c = blockIdx.x, s = blockIdx.y, tid = threadIdx.x;
  float s1 = 0.f, s2 = 0.f;
  for (int bb = 0; bb < Bper; ++bb) {
    const float* p = y + ((long)(s * Bper + bb) * C + c) * HW;
    for (int i = tid; i < HW; i += 256) { float v = p[i]; s1 += v; s2 += v * v; }
  }
  for (int o = 32; o; o >>= 1) { s1 += __shfl_xor(s1, o); s2 += __shfl_xor(s2, o); }
  __shared__ float r1[4], r2[4];
  int wv = tid >> 6;
  if ((tid & 63) == 0) { r1[wv] = s1; r2[wv] = s2; }
  __syncthreads();
  if (tid == 0) {
    s1 = r1[0] + r1[1] + r1[2] + r1[3];
    s2 = r2[0] + r2[1] + r2[2] + r2[3];
    atomicAdd(&sums[c], s1);
    atomicAdd(&sums[C + c], s2);
  }
}

__global__ void k_bn_finalize(const float* __restrict__ sums, const float* __restrict__ g,
    const float* __restrict__ b, float* __restrict__ scale, float* __restrict__ shift,
    int C, float invN)
{
  int c = threadIdx.x;
  if (c < C) {
    float m = sums[c] * invN;
    float var = sums[C + c] * invN - m * m;
    float sc = g[c] * rsqrtf(var + 1e-5f);
    scale[c] = sc;
    shift[c] = b[c] - m * sc;
  }
}

__global__ __launch_bounds__(256) void k_bn_apply(float* __restrict__ y,
    const float* __restrict__ scale, const float* __restrict__ shift, int C, int HW)
{
  int bc = blockIdx.x;
  int c = bc % C;
  float sc = scale[c], sh = shift[c];
  float* p = y + (long)bc * HW;
  for (int i = threadIdx.x; i < HW; i += 256) p[i] = gelu_f(p[i] * sc + sh);
}

// ---------------- conv2: a1[1024,32,35,39] * w[64,32,4,4] s2 -> y[1024,64,16,18]
__global__ __launch_bounds__(256) void k_conv2(const float* __restrict__ a1,
    const float* __restrict__ w, const float* __restrict__ bias, float* __restrict__ y)
{
  __shared__ float ins[12480 + 8];    // [c:32][r:10][col:39]
  __shared__ float ws2[16384];        // 32 oc chunk: [ocl][c:32][kh:4][kw:4]
  int b = blockIdx.y, oh0 = blockIdx.x * 4, tid = threadIdx.x;
  for (int i = tid; i < 12480; i += 256) {
    int c = i / 390, rr = (i % 390) / 39, col = i % 39;
    int row = oh0 * 2 + rr;
    ins[i] = a1[(((long)b * 32 + c) * 35 + row) * 39 + col];
  }
  for (int ocg = 0; ocg < 2; ++ocg) {
    __syncthreads();
    for (int i = tid; i < 16384; i += 256) ws2[i] = w[ocg * 16384 + i];
    __syncthreads();
    int t = tid;
    if (t < 192) {
      int og = t / 24, rem = t % 24, ohl = rem / 6, owg = rem % 6;
      int oc0l = og * 4, ow0 = owg * 3, oh = oh0 + ohl;
      float acc[4][3] = {};
      for (int c = 0; c < 32; ++c)
#pragma unroll
        for (int kh = 0; kh < 4; ++kh) {
          const float* ip = &ins[c * 390 + (ohl * 2 + kh) * 39 + ow0 * 2];
          const float* wp = &ws2[oc0l * 512 + c * 16 + kh * 4];
#pragma unroll
          for (int kw = 0; kw < 4; ++kw) {
            float i0 = ip[kw], i1 = ip[kw + 2], i2 = ip[kw + 4];
            float w0 = wp[kw], w1 = wp[kw + 512], w2 = wp[kw + 1024], w3 = wp[kw + 1536];
            acc[0][0] += w0 * i0; acc[0][1] += w0 * i1; acc[0][2] += w0 * i2;
            acc[1][0] += w1 * i0; acc[1][1] += w1 * i1; acc[1][2] += w1 * i2;
            acc[2][0] += w2 * i0; acc[2][1] += w2 * i1; acc[2][2] += w2 * i2;
            acc[3][0] += w3 * i0; acc[3][1] += w3 * i1; acc[3][2] += w3 * i2;
          }
        }
      for (int i = 0; i < 4; ++i) {
        int oc = ocg * 32 + oc0l + i;
        float bv = bias[oc];
        for (int j = 0; j < 3; ++j)
          y[(((long)b * 64 + oc) * 16 + oh) * 18 + ow0 + j] = acc[i][j] + bv;
      }
    }
  }
}

// ---------------- conv3: a2[1024,64,16,18] * w[128,64,3,3] s1 -> y[1024,128,14,16]
__global__ __launch_bounds__(256) void k_conv3(const float* __restrict__ a2,
    const float* __restrict__ w, const float* __restrict__ bias, float* __restrict__ y)
{
  __shared__ float ins[18432];        // [c:64][r:16][col:18]
  __shared__ float ws3[9216];         // 16 oc chunk: [ocl][c:64][kh:3][kw:3]
  int b = blockIdx.x, tid = threadIdx.x;
  const float4* src = (const float4*)(a2 + (long)b * 18432);
  float4* dst = (float4*)ins;
  for (int i = tid; i < 4608; i += 256) dst[i] = src[i];
  for (int ocg = 0; ocg < 8; ++ocg) {
    __syncthreads();
    for (int i = tid; i < 9216; i += 256) ws3[i] = w[ocg * 9216 + i];
    __syncthreads();
    int t = tid;
    if (t < 224) {
      int ocl = (t / 56) * 4, oh = (t % 56) / 4, ow0 = (t % 4) * 4;
      float acc[4][4] = {};
      for (int c = 0; c < 64; ++c)
#pragma unroll
        for (int kh = 0; kh < 3; ++kh) {
          const float* ip = &ins[c * 288 + (oh + kh) * 18 + ow0];
          const float* wp = &ws3[ocl * 576 + c * 9 + kh * 3];
#pragma unroll
          for (int kw = 0; kw < 3; ++kw) {
            float i0 = ip[kw], i1 = ip[kw + 1], i2 = ip[kw + 2], i3 = ip[kw + 3];
            float w0 = wp[kw], w1 = wp[kw + 576], w2 = wp[kw + 1152], w3 = wp[kw + 1728];
            acc[0][0] += w0 * i0; acc[0][1] += w0 * i1; acc[0][2] += w0 * i2; acc[0][3] += w0 * i3;
            acc[1][0] += w1 * i0; acc[1][1] += w1 * i1; acc[1][2] += w1 * i2; acc[1][3] += w1 * i3;
            acc[2][0] += w2 * i0; acc[2][1] += w2 * i1; acc[2][2] += w2 * i2; acc[2][3] += w2 * i3;
            acc[3][0] += w3 * i0; acc[3][1] += w3 * i1; acc[3][2] += w3 * i2; acc[3][3] += w3 * i3;
          }
        }
      for (int i = 0; i < 4; ++i) {
        int oc = ocg * 16 + ocl + i;
        float bv = bias[oc];
        for (int j = 0; j < 4; ++j)
          y[(((long)b * 128 + oc) * 14 + oh) * 16 + ow0 + j] = acc[i][j] + bv;
      }
    }
  }
}

// ---------------- generic fp32 GEMM: C[M,N] = A[M,K] * B[N,K]^T (+bias, +gelu)
// tile 64x64, 256 threads, 4x4/thread, K-step 32. M,N multiples of 64; K of 32.
__global__ __launch_bounds__(256) void k_gemm64(const float* __restrict__ A, int lda,
    const float* __restrict__ B, int ldb, const float* __restrict__ bias,
    float* __restrict__ C, int ldc, int K,
    long aZ, long bZ, long cZ, int biasZ, int act)
{
  int z = blockIdx.z;
  A += (long)z * aZ; B += (long)z * bZ; C += (long)z * cZ;
  int m0 = blockIdx.x * 64, n0 = blockIdx.y * 64, tid = threadIdx.x;
  int tx = tid & 15, ty = tid >> 4;
  __shared__ float As[32][68], Bs[32][68];
  float acc[4][4] = {};
  for (int kt = 0; kt < K; kt += 32) {
#pragma unroll
    for (int s = 0; s < 2; ++s) {
      int t = tid + s * 256;
      int row = t >> 3, kq = (t & 7) * 4;
      float4 av = *(const float4*)(A + (long)(m0 + row) * lda + kt + kq);
      As[kq + 0][row] = av.x; As[kq + 1][row] = av.y; As[kq + 2][row] = av.z; As[kq + 3][row] = av.w;
      float4 bvv = *(const float4*)(B + (long)(n0 + row) * ldb + kt + kq);
      Bs[kq + 0][row] = bvv.x; Bs[kq + 1][row] = bvv.y; Bs[kq + 2][row] = bvv.z; Bs[kq + 3][row] = bvv.w;
    }
    __syncthreads();
#pragma unroll
    for (int kk = 0; kk < 32; ++kk) {
      float4 a4 = *(const float4*)&As[kk][ty * 4];
      float4 b4 = *(const float4*)&Bs[kk][tx * 4];
      acc[0][0] += a4.x * b4.x; acc[0][1] += a4.x * b4.y; acc[0][2] += a4.x * b4.z; acc[0][3] += a4.x * b4.w;
      acc[1][0] += a4.y * b4.x; acc[1][1] += a4.y * b4.y; acc[1][2] += a4.y * b4.z; acc[1][3] += a4.y * b4.w;
      acc[2][0] += a4.z * b4.x; acc[2][1] += a4.z * b4.y; acc[2][2] += a4.z * b4.z; acc[2][3] += a4.z * b4.w;
      acc[3][0] += a4.w * b4.x; acc[3][1] += a4.w * b4.y; acc[3][2] += a4.w * b4.z; acc[3][3] += a4.w * b4.w;
    }
    __syncthreads();
  }
  float bv[4] = {0.f, 0.f, 0.f, 0.f};
  if (bias) {
    const float* bp = bias + (long)z * biasZ + n0 + tx * 4;
    bv[0] = bp[0]; bv[1] = bp[1]; bv[2] = bp[2]; bv[3] = bp[3];
  }
  for (int i = 0; i < 4; ++i) {
    float* op = C + (long)(m0 + ty * 4 + i) * ldc + n0 + tx * 4;
    float4 o;
    o.x = acc[i][0] + bv[0]; o.y = acc[i][1] + bv[1];
    o.z = acc[i][2] + bv[2]; o.w = acc[i][3] + bv[3];
    if (act) { o.x = gelu_f(o.x); o.y = gelu_f(o.y); o.z = gelu_f(o.z); o.w = gelu_f(o.w); }
    *(float4*)op = o;
  }
}

// ---------------- proj split-K reduce + bias ----------------
__global__ __launch_bounds__(256) void k_proj_reduce(const float* __restrict__ parts,
    const float* __restrict__ bias, float* __restrict__ t)
{
  int i = blockIdx.x * 256 + threadIdx.x;
  float s = 0.f;
#pragma unroll
  for (int z = 0; z < 8; ++z) s += parts[(long)z * 262144 + i];
  t[i] = s + bias[i & 255];
}

// ---------------- LN + GELU over D=256 ----------------
__global__ __launch_bounds__(256) void k_ln_gelu(const float* __restrict__ t,
    const float* __restrict__ g, const float* __restrict__ bb, float* __restrict__ h)
{
  int b = blockIdx.x, d = threadIdx.x;
  float v = t[b * 256 + d];
  __shared__ float red[4];
  float s = v;
  for (int o = 32; o; o >>= 1) s += __shfl_xor(s, o);
  if ((d & 63) == 0) red[d >> 6] = s;
  __syncthreads();
  float mean = (red[0] + red[1] + red[2] + red[3]) * (1.f / 256.f);
  __syncthreads();
  float dv = v - mean;
  s = dv * dv;
  for (int o = 32; o; o >>= 1) s += __shfl_xor(s, o);
  if ((d & 63) == 0) red[d >> 6] = s;
  __syncthreads();
  float var = (red[0] + red[1] + red[2] + red[3]) * (1.f / 256.f);
  float y = g[d] * dv * rsqrtf(var + 1e-5f) + bb[d];
  h[b * 256 + d] = gelu_f(y);
}

// ---------------- router: logits, softmax, top-2, aux-loss accumulators ----------------
__global__ __launch_bounds__(64) void k_router(const float* __restrict__ h,
    const float* __restrict__ rw, const float* __restrict__ eb,
    float* __restrict__ wts, int* __restrict__ idx,
    float* __restrict__ pm_sum, float* __restrict__ z_sum)
{
  int b = blockIdx.x, lane = threadIdx.x;
  float4 hv = *(const float4*)(h + b * 256 + lane * 4);
  float logit[8];
#pragma unroll
  for (int e = 0; e < 8; ++e) {
    float4 wv = *(const float4*)(rw + e * 256 + lane * 4);
    float p = hv.x * wv.x + hv.y * wv.y + hv.z * wv.z + hv.w * wv.w;
    for (int o = 32; o; o >>= 1) p += __shfl_xor(p, o);
    logit[e] = p + eb[e];
  }
  float mx = logit[0];
#pragma unroll
  for (int e = 1; e < 8; ++e) mx = fmaxf(mx, logit[e]);
  float pr[8]; float se = 0.f;
#pragma unroll
  for (int e = 0; e < 8; ++e) { pr[e] = expf(logit[e] - mx); se += pr[e]; }
  float inv = 1.f / se;
#pragma unroll
  for (int e = 0; e < 8; ++e) pr[e] *= inv;
  int i0 = 0; float v0 = pr[0];
#pragma unroll
  for (int e = 1; e < 8; ++e) if (pr[e] > v0) { v0 = pr[e]; i0 = e; }
  int i1 = -1; float v1 = -1.f;
#pragma unroll
  for (int e = 0; e < 8; ++e) if (e != i0 && pr[e] > v1) { v1 = pr[e]; i1 = e; }
  if (lane == 0) {
    float ssum = v0 + v1 + 1e-8f;
    wts[2 * b] = v0 / ssum; wts[2 * b + 1] = v1 / ssum;
    idx[2 * b] = i0; idx[2 * b + 1] = i1;
    float zz = 0.f;
#pragma unroll
    for (int e = 0; e < 8; ++e) zz += logit[e] * logit[e];
    atomicAdd(z_sum, zz);
  }
  if (lane < 8) atomicAdd(&pm_sum[lane], pr[lane]);
}

// ---------------- combine top-2 + 0.5*shared, then final LN ----------------
__global__ __launch_bounds__(256) void k_combine_ln(const float* __restrict__ eout,
    const float* __restrict__ sharedB, const float* __restrict__ wts, const int* __restrict__ idx,
    const float* __restrict__ g, const float* __restrict__ bb, float* __restrict__ out)
{
  int b = blockIdx.x, d = threadIdx.x;
  float w0 = wts[2 * b], w1 = wts[2 * b + 1];
  int i0 = idx[2 * b], i1 = idx[2 * b + 1];
  float val = w0 * eout[(long)i0 * 262144 + b * 256 + d]
            + w1 * eout[(long)i1 * 262144 + b * 256 + d]
            + 0.5f * sharedB[b * 256 + d];
  __shared__ float red[4];
  float s = val;
  for (int o = 32; o; o >>= 1) s += __shfl_xor(s, o);
  if ((d & 63) == 0) red[d >> 6] = s;
  __syncthreads();
  float mean = (red[0] + red[1] + red[2] + red[3]) * (1.f / 256.f);
  __syncthreads();
  float dv = val - mean;
  s = dv * dv;
  for (int o = 32; o; o >>= 1) s += __shfl_xor(s, o);
  if ((d & 63) == 0) red[d >> 6] = s;
  __syncthreads();
  float var = (red[0] + red[1] + red[2] + red[3]) * (1.f / 256.f);
  out[b * 256 + d] = g[d] * dv * rsqrtf(var + 1e-5f) + bb[d];
}

// ---------------- aux losses ----------------
__global__ void k_losses(const float* __restrict__ pm_sum, const float* __restrict__ z_sum,
                         float* __restrict__ out)
{
  if (threadIdx.x == 0 && blockIdx.x == 0) {
    float lb = 0.f;
    for (int e = 0; e < 8; ++e) {
      float pm = pm_sum[e] * (1.f / 1024.f);
      float dd = pm - 0.125f;
      lb += dd * dd;
    }
    out[262144] = lb * 8.f;
    out[262145] = z_sum[0] * (1.f / 8192.f) * 0.001f;
  }
}

extern "C" void kernel_launch(void* const* d_in, const int* in_sizes, int n_in,
                              void* d_out, int out_size, void* d_ws, size_t ws_size,
                              hipStream_t stream)
{
  const float* x     = (const float*)d_in[0];
  const float* c1w   = (const float*)d_in[1];
  const float* c1b   = (const float*)d_in[2];
  const float* bn1g  = (const float*)d_in[3];
  const float* bn1b  = (const float*)d_in[4];
  const float* c2w   = (const float*)d_in[5];
  const float* c2b   = (const float*)d_in[6];
  const float* bn2g  = (const float*)d_in[7];
  const float* bn2b  = (const float*)d_in[8];
  const float* c3w   = (const float*)d_in[9];
  const float* c3b   = (const float*)d_in[10];
  const float* bn3g  = (const float*)d_in[11];
  const float* bn3b  = (const float*)d_in[12];
  const float* projw = (const float*)d_in[13];
  const float* projb = (const float*)d_in[14];
  const float* lng   = (const float*)d_in[15];
  const float* lnb   = (const float*)d_in[16];
  const float* rw    = (const float*)d_in[17];
  const float* ebias = (const float*)d_in[18];
  const float* ew1   = (const float*)d_in[19];
  const float* eb1   = (const float*)d_in[20];
  const float* ew2   = (const float*)d_in[21];
  const float* eb2   = (const float*)d_in[22];
  const float* sw1   = (const float*)d_in[23];
  const float* sb1   = (const float*)d_in[24];
  const float* sw2   = (const float*)d_in[25];
  const float* sb2   = (const float*)d_in[26];
  const float* mlng  = (const float*)d_in[27];
  const float* mlnb  = (const float*)d_in[28];
  float* out = (float*)d_out;

  float* W = (float*)d_ws;
  float* y1    = W;                      // 44,728,320 floats (also y3/act3 alias)
  float* y2    = W + 44728320L;          // 18,874,368
  float* hid   = W + 63602688L;          // 4,194,304
  float* eoutB = W + 67796992L;          // 2,097,152
  float* parts = W + 69894144L;          // 2,097,152 (8 x 262144)
  float* tbuf  = W + 71991296L;          // 262,144
  float* hbuf  = W + 72253440L;          // 262,144
  float* sh1   = W + 72515584L;          // 262,144
  float* shB   = W + 72777728L;          // 262,144
  float* stats = W + 73039872L;          // 1,024
  float* wtsb  = W + 73040896L;          // 2,048
  int*   idxb  = (int*)(W + 73042944L);  // 2,048
  float* y3 = y1;

  float* sums1 = stats;        float* scale1 = stats + 512; float* shift1 = stats + 544;
  float* sums2 = stats + 64;   float* scale2 = stats + 576; float* shift2 = stats + 640;
  float* sums3 = stats + 192;  float* scale3 = stats + 704; float* shift3 = stats + 832;
  float* pm    = stats + 448;  float* zsum   = stats + 456;

  dim3 blk(256);
  k_zero<<<dim3(2), blk, 0, stream>>>(stats, 512);

  k_conv1<<<dim3(12, 1024), blk, 0, stream>>>(x, c1w, c1b, y1);
  k_bn_stats<<<dim3(32, 32), blk, 0, stream>>>(y1, sums1, 32, 1365, 32);
  k_bn_finalize<<<1, 32, 0, stream>>>(sums1, bn1g, bn1b, scale1, shift1, 32, 1.f / 1397760.f);
  k_bn_apply<<<dim3(32768), blk, 0, stream>>>(y1, scale1, shift1, 32, 1365);

  k_conv2<<<dim3(4, 1024), blk, 0, stream>>>(y1, c2w, c2b, y2);
  k_bn_stats<<<dim3(64, 16), blk, 0, stream>>>(y2, sums2, 64, 288, 64);
  k_bn_finalize<<<1, 64, 0, stream>>>(sums2, bn2g, bn2b, scale2, shift2, 64, 1.f / 294912.f);
  k_bn_apply<<<dim3(65536), blk, 0, stream>>>(y2, scale2, shift2, 64, 288);

  k_conv3<<<dim3(1024), blk, 0, stream>>>(y2, c3w, c3b, y3);
  k_bn_stats<<<dim3(128, 32), blk, 0, stream>>>(y3, sums3, 128, 224, 32);
  k_bn_finalize<<<1, 128, 0, stream>>>(sums3, bn3g, bn3b, scale3, shift3, 128, 1.f / 229376.f);
  k_bn_apply<<<dim3(131072), blk, 0, stream>>>(y3, scale3, shift3, 128, 224);

  // proj: [1024,28672] x [256,28672]^T, split-K=8
  k_gemm64<<<dim3(16, 4, 8), blk, 0, stream>>>(y3, 28672, projw, 28672, nullptr,
                                               parts, 256, 3584, 3584L, 3584L, 262144L, 0, 0);
  k_proj_reduce<<<dim3(1024), blk, 0, stream>>>(parts, projb, tbuf);
  k_ln_gelu<<<dim3(1024), blk, 0, stream>>>(tbuf, lng, lnb, hbuf);

  k_router<<<dim3(1024), dim3(64), 0, stream>>>(hbuf, rw, ebias, wtsb, idxb, pm, zsum);

  // dense experts: hid = gelu(h @ ew1^T + eb1); eout = hid @ ew2^T + eb2
  k_gemm64<<<dim3(16, 8, 8), blk, 0, stream>>>(hbuf, 256, ew1, 256, eb1,
                                               hid, 512, 256, 0L, 131072L, 524288L, 512, 1);
  k_gemm64<<<dim3(16, 4, 8), blk, 0, stream>>>(hid, 512, ew2, 512, eb2,
                                               eoutB, 256, 512, 524288L, 131072L, 262144L, 256, 0);
  // shared expert
  k_gemm64<<<dim3(16, 4, 1), blk, 0, stream>>>(hbuf, 256, sw1, 256, sb1,
                                               sh1, 256, 256, 0L, 0L, 0L, 0, 1);
  k_gemm64<<<dim3(16, 4, 1), blk, 0, stream>>>(sh1, 256, sw2, 256, sb2,
                                               shB, 256, 256, 0L, 0L, 0L, 0, 0);

  k_combine_ln<<<dim3(1024), blk, 0, stream>>>(eoutB, shB, wtsb, idxb, mlng, mlnb, out);
  k_losses<<<1, 64, 0, stream>>>(pm, zsum, out);
}

// Round 2
// 3331.570 us; speedup vs baseline: 7.8406x; 7.8406x over previous
//
#include <hip/hip_runtime.h>
#include <hip/hip_bf16.h>
#include <math.h>

#define DEV __device__ __forceinline__

DEV float gelu_f(float x) { return 0.5f * x * (1.0f + erff(x * 0.70710678118654752f)); }

// ---------------- zero stats region ----------------
__global__ void k_zero(float* p, int n) {
  int i = blockIdx.x * blockDim.x + threadIdx.x;
  if (i < n) p[i] = 0.f;
}

// ---------------- conv1 weight pre-transpose: w[32][4][8][8] -> wt[256][32]
__global__ void k_wt1(const float* __restrict__ w, float* __restrict__ wt) {
  int i = blockIdx.x * 256 + threadIdx.x;   // i = k*32 + oc
  if (i < 8192) {
    int k = i >> 5, oc = i & 31;
    wt[i] = w[oc * 256 + k];
  }
}

// ---------------- conv1: x[1024,4,144,160] * w[32,4,8,8] s4 -> y[1024,32,35,39]
// LDS input de-interleaved by col%4: ins_di[c][m][r][q] = x[c, row0+r, 4q+m]
// m-plane stride 708 (16*44 + 4 pad), row stride 44 (40 q + 4 pad).
__global__ __launch_bounds__(256) void k_conv1(const float* __restrict__ x,
    const float* __restrict__ wt, const float* __restrict__ bias, float* __restrict__ y)
{
  __shared__ float ins_di[11328];     // 4 * 2832
  __shared__ float ws_t[8192];        // [k:256][oc:32]
  int b = blockIdx.y, oh0 = blockIdx.x * 3, tid = threadIdx.x;
  int row0 = oh0 * 4;
  for (int i = tid; i < 8192; i += 256) ws_t[i] = wt[i];
  for (int i = tid; i < 10240; i += 256) {
    int c = i / 2560, rem = i % 2560, r = rem / 160, col = rem % 160;
    int row = row0 + r;
    float v = (row < 144) ? x[(((long)b * 4 + c) * 144 + row) * 160 + col] : 0.f;
    ins_di[c * 2832 + (col & 3) * 708 + r * 44 + (col >> 2)] = v;
  }
  __syncthreads();
  int t = tid;
  if (t >= 240) return;
  int ocq = t / 30, rem = t % 30, ohl = rem / 10, owg = rem % 10;
  int oh = oh0 + ohl;
  if (oh >= 35) return;
  int oc0 = ocq * 4, ow0 = owg * 4;
  float acc[4][4] = {};
#pragma unroll 1
  for (int c = 0; c < 4; ++c) {
#pragma unroll 1
    for (int kh = 0; kh < 8; ++kh) {
      const float* irow = &ins_di[c * 2832 + (ohl * 4 + kh) * 44 + ow0];
      const float* wrow = &ws_t[(c * 64 + kh * 8) * 32 + oc0];
#pragma unroll
      for (int m = 0; m < 4; ++m) {
        float4 A = *(const float4*)(irow + m * 708);
        float s  = irow[m * 708 + 4];
        float4 w0 = *(const float4*)(wrow + m * 32);        // kw = m
        float4 w1 = *(const float4*)(wrow + (m + 4) * 32);  // kw = m+4
        acc[0][0] += w0.x * A.x; acc[0][1] += w0.x * A.y; acc[0][2] += w0.x * A.z; acc[0][3] += w0.x * A.w;
        acc[1][0] += w0.y * A.x; acc[1][1] += w0.y * A.y; acc[1][2] += w0.y * A.z; acc[1][3] += w0.y * A.w;
        acc[2][0] += w0.z * A.x; acc[2][1] += w0.z * A.y; acc[2][2] += w0.z * A.z; acc[2][3] += w0.z * A.w;
        acc[3][0] += w0.w * A.x; acc[3][1] += w0.w * A.y; acc[3][2] += w0.w * A.z; acc[3][3] += w0.w * A.w;
        acc[0][0] += w1.x * A.y; acc[0][1] += w1.x * A.z; acc[0][2] += w1.x * A.w; acc[0][3] += w1.x * s;
        acc[1][0] += w1.y * A.y; acc[1][1] += w1.y * A.z; acc[1][2] += w1.y * A.w; acc[1][3] += w1.y * s;
        acc[2][0] += w1.z * A.y; acc[2][1] += w1.z * A.z; acc[2][2] += w1.z * A.w; acc[2][3] += w1.z * s;
        acc[3][0] += w1.w * A.y; acc[3][1] += w1.w * A.z; acc[3][2] += w1.w * A.w; acc[3][3] += w1.w * s;
      }
    }
  }
  for (int i = 0; i < 4; ++i) {
    float bv = bias[oc0 + i];
    for (int j = 0; j < 4; ++j) {
      int ow = ow0 + j;
      if (ow < 39)
        y[(((long)b * 32 + oc0 + i) * 35 + oh) * 39 + ow] = acc[i][j] + bv;
    }
  }
}

// ---------------- BN stats (sum, sumsq per channel) ----------------
__global__ __launch_bounds__(256) void k_bn_stats(const float* __restrict__ y,
    float* __restrict__ sums, int C, int HW, int Bper)
{
  int c = blockIdx.x, s = blockIdx.y, tid = threadIdx.x;
  float s1 = 0.f, s2 = 0.f;
  for (int bb = 0; bb < Bper; ++bb) {
    const float* p = y + ((long)(s * Bper + bb) * C + c) * HW;
    for (int i = tid; i < HW; i += 256) { float v = p[i]; s1 += v; s2 += v * v; }
  }
  for (int o = 32; o; o >>= 1) { s1 += __shfl_xor(s1, o); s2 += __shfl_xor(s2, o); }
  __shared__ float r1[4], r2[4];
  int wv = tid >> 6;
  if ((tid & 63) == 0) { r1[wv] = s1; r2[wv] = s2; }
  __syncthreads();
  if (tid == 0) {
    s1 = r1[0] + r1[1] + r1[2] + r1[3];
    s2 = r2[0] + r2[1] + r2[2] + r2[3];
    atomicAdd(&sums[c], s1);
    atomicAdd(&sums[C + c], s2);
  }
}

__global__ void k_bn_finalize(const float* __restrict__ sums, const float* __restrict__ g,
    const float* __restrict__ b, float* __restrict__ scale, float* __restrict__ shift,
    int C, float invN)
{
  int c = threadIdx.x;
  if (c < C) {
    float m = sums[c] * invN;
    float var = sums[C + c] * invN - m * m;
    float sc = g[c] * rsqrtf(var + 1e-5f);
    scale[c] = sc;
    shift[c] = b[c] - m * sc;
  }
}

__global__ __launch_bounds__(256) void k_bn_apply(float* __restrict__ y,
    const float* __restrict__ scale, const float* __restrict__ shift, int C, int HW)
{
  int bc = blockIdx.x;
  int c = bc % C;
  float sc = scale[c], sh = shift[c];
  float* p = y + (long)bc * HW;
  for (int i = threadIdx.x; i < HW; i += 256) p[i] = gelu_f(p[i] * sc + sh);
}

// ---------------- conv2: a1[1024,32,35,39] * w[64,32,4,4] s2 -> y[1024,64,16,18]
__global__ __launch_bounds__(256) void k_conv2(const float* __restrict__ a1,
    const float* __restrict__ w, const float* __restrict__ bias, float* __restrict__ y)
{
  __shared__ float ins[12480 + 8];    // [c:32][r:10][col:39]
  __shared__ float ws2[16384];        // 32 oc chunk: [ocl][c:32][kh:4][kw:4]
  int b = blockIdx.y, oh0 = blockIdx.x * 4, tid = threadIdx.x;
  for (int i = tid; i < 12480; i += 256) {
    int c = i / 390, rr = (i % 390) / 39, col = i % 39;
    int row = oh0 * 2 + rr;
    ins[i] = a1[(((long)b * 32 + c) * 35 + row) * 39 + col];
  }
  for (int ocg = 0; ocg < 2; ++ocg) {
    __syncthreads();
    for (int i = tid; i < 16384; i += 256) ws2[i] = w[ocg * 16384 + i];
    __syncthreads();
    int t = tid;
    if (t < 192) {
      int og = t / 24, rem = t % 24, ohl = rem / 6, owg = rem % 6;
      int oc0l = og * 4, ow0 = owg * 3, oh = oh0 + ohl;
      float acc[4][3] = {};
#pragma unroll 1
      for (int c = 0; c < 32; ++c)
#pragma unroll
        for (int kh = 0; kh < 4; ++kh) {
          const float* ip = &ins[c * 390 + (ohl * 2 + kh) * 39 + ow0 * 2];
          const float* wp = &ws2[oc0l * 512 + c * 16 + kh * 4];
#pragma unroll
          for (int kw = 0; kw < 4; ++kw) {
            float i0 = ip[kw], i1 = ip[kw + 2], i2 = ip[kw + 4];
            float w0 = wp[kw], w1 = wp[kw + 512], w2 = wp[kw + 1024], w3 = wp[kw + 1536];
            acc[0][0] += w0 * i0; acc[0][1] += w0 * i1; acc[0][2] += w0 * i2;
            acc[1][0] += w1 * i0; acc[1][1] += w1 * i1; acc[1][2] += w1 * i2;
            acc[2][0] += w2 * i0; acc[2][1] += w2 * i1; acc[2][2] += w2 * i2;
            acc[3][0] += w3 * i0; acc[3][1] += w3 * i1; acc[3][2] += w3 * i2;
          }
        }
      for (int i = 0; i < 4; ++i) {
        int oc = ocg * 32 + oc0l + i;
        float bv = bias[oc];
        for (int j = 0; j < 3; ++j)
          y[(((long)b * 64 + oc) * 16 + oh) * 18 + ow0 + j] = acc[i][j] + bv;
      }
    }
  }
}

// ---------------- conv3: a2[1024,64,16,18] * w[128,64,3,3] s1 -> y[1024,128,14,16]
__global__ __launch_bounds__(256) void k_conv3(const float* __restrict__ a2,
    const float* __restrict__ w, const float* __restrict__ bias, float* __restrict__ y)
{
  __shared__ float ins[18432];        // [c:64][r:16][col:18]
  __shared__ float ws3[9216];         // 16 oc chunk: [ocl][c:64][kh:3][kw:3]
  int b = blockIdx.x, tid = threadIdx.x;
  const float4* src = (const float4*)(a2 + (long)b * 18432);
  float4* dst = (float4*)ins;
  for (int i = tid; i < 4608; i += 256) dst[i] = src[i];
  for (int ocg = 0; ocg < 8; ++ocg) {
    __syncthreads();
    for (int i = tid; i < 9216; i += 256) ws3[i] = w[ocg * 9216 + i];
    __syncthreads();
    int t = tid;
    if (t < 224) {
      int ocl = (t / 56) * 4, oh = (t % 56) / 4, ow0 = (t % 4) * 4;
      float acc[4][4] = {};
#pragma unroll 1
      for (int c = 0; c < 64; ++c)
#pragma unroll
        for (int kh = 0; kh < 3; ++kh) {
          const float* ip = &ins[c * 288 + (oh + kh) * 18 + ow0];
          const float* wp = &ws3[ocl * 576 + c * 9 + kh * 3];
#pragma unroll
          for (int kw = 0; kw < 3; ++kw) {
            float i0 = ip[kw], i1 = ip[kw + 1], i2 = ip[kw + 2], i3 = ip[kw + 3];
            float w0 = wp[kw], w1 = wp[kw + 576], w2 = wp[kw + 1152], w3 = wp[kw + 1728];
            acc[0][0] += w0 * i0; acc[0][1] += w0 * i1; acc[0][2] += w0 * i2; acc[0][3] += w0 * i3;
            acc[1][0] += w1 * i0; acc[1][1] += w1 * i1; acc[1][2] += w1 * i2; acc[1][3] += w1 * i3;
            acc[2][0] += w2 * i0; acc[2][1] += w2 * i1; acc[2][2] += w2 * i2; acc[2][3] += w2 * i3;
            acc[3][0] += w3 * i0; acc[3][1] += w3 * i1; acc[3][2] += w3 * i2; acc[3][3] += w3 * i3;
          }
        }
      for (int i = 0; i < 4; ++i) {
        int oc = ocg * 16 + ocl + i;
        float bv = bias[oc];
        for (int j = 0; j < 4; ++j)
          y[(((long)b * 128 + oc) * 14 + oh) * 16 + ow0 + j] = acc[i][j] + bv;
      }
    }
  }
}

// ---------------- generic fp32 GEMM: C[M,N] = A[M,K] * B[N,K]^T (+bias, +gelu)
__global__ __launch_bounds__(256) void k_gemm64(const float* __restrict__ A, int lda,
    const float* __restrict__ B, int ldb, const float* __restrict__ bias,
    float* __restrict__ C, int ldc, int K,
    long aZ, long bZ, long cZ, int biasZ, int act)
{
  int z = blockIdx.z;
  A += (long)z * aZ; B += (long)z * bZ; C += (long)z * cZ;
  int m0 = blockIdx.x * 64, n0 = blockIdx.y * 64, tid = threadIdx.x;
  int tx = tid & 15, ty = tid >> 4;
  __shared__ float As[32][68], Bs[32][68];
  float acc[4][4] = {};
  for (int kt = 0; kt < K; kt += 32) {
#pragma unroll
    for (int s = 0; s < 2; ++s) {
      int t = tid + s * 256;
      int row = t >> 3, kq = (t & 7) * 4;
      float4 av = *(const float4*)(A + (long)(m0 + row) * lda + kt + kq);
      As[kq + 0][row] = av.x; As[kq + 1][row] = av.y; As[kq + 2][row] = av.z; As[kq + 3][row] = av.w;
      float4 bvv = *(const float4*)(B + (long)(n0 + row) * ldb + kt + kq);
      Bs[kq + 0][row] = bvv.x; Bs[kq + 1][row] = bvv.y; Bs[kq + 2][row] = bvv.z; Bs[kq + 3][row] = bvv.w;
    }
    __syncthreads();
#pragma unroll
    for (int kk = 0; kk < 32; ++kk) {
      float4 a4 = *(const float4*)&As[kk][ty * 4];
      float4 b4 = *(const float4*)&Bs[kk][tx * 4];
      acc[0][0] += a4.x * b4.x; acc[0][1] += a4.x * b4.y; acc[0][2] += a4.x * b4.z; acc[0][3] += a4.x * b4.w;
      acc[1][0] += a4.y * b4.x; acc[1][1] += a4.y * b4.y; acc[1][2] += a4.y * b4.z; acc[1][3] += a4.y * b4.w;
      acc[2][0] += a4.z * b4.x; acc[2][1] += a4.z * b4.y; acc[2][2] += a4.z * b4.z; acc[2][3] += a4.z * b4.w;
      acc[3][0] += a4.w * b4.x; acc[3][1] += a4.w * b4.y; acc[3][2] += a4.w * b4.z; acc[3][3] += a4.w * b4.w;
    }
    __syncthreads();
  }
  float bv[4] = {0.f, 0.f, 0.f, 0.f};
  if (bias) {
    const float* bp = bias + (long)z * biasZ + n0 + tx * 4;
    bv[0] = bp[0]; bv[1] = bp[1]; bv[2] = bp[2]; bv[3] = bp[3];
  }
  for (int i = 0; i < 4; ++i) {
    float* op = C + (long)(m0 + ty * 4 + i) * ldc + n0 + tx * 4;
    float4 o;
    o.x = acc[i][0] + bv[0]; o.y = acc[i][1] + bv[1];
    o.z = acc[i][2] + bv[2]; o.w = acc[i][3] + bv[3];
    if (act) { o.x = gelu_f(o.x); o.y = gelu_f(o.y); o.z = gelu_f(o.z); o.w = gelu_f(o.w); }
    *(float4*)op = o;
  }
}

// ---------------- proj split-K reduce + bias ----------------
__global__ __launch_bounds__(256) void k_proj_reduce(const float* __restrict__ parts,
    const float* __restrict__ bias, float* __restrict__ t)
{
  int i = blockIdx.x * 256 + threadIdx.x;
  float s = 0.f;
#pragma unroll
  for (int z = 0; z < 8; ++z) s += parts[(long)z * 262144 + i];
  t[i] = s + bias[i & 255];
}

// ---------------- LN + GELU over D=256 ----------------
__global__ __launch_bounds__(256) void k_ln_gelu(const float* __restrict__ t,
    const float* __restrict__ g, const float* __restrict__ bb, float* __restrict__ h)
{
  int b = blockIdx.x, d = threadIdx.x;
  float v = t[b * 256 + d];
  __shared__ float red[4];
  float s = v;
  for (int o = 32; o; o >>= 1) s += __shfl_xor(s, o);
  if ((d & 63) == 0) red[d >> 6] = s;
  __syncthreads();
  float mean = (red[0] + red[1] + red[2] + red[3]) * (1.f / 256.f);
  __syncthreads();
  float dv = v - mean;
  s = dv * dv;
  for (int o = 32; o; o >>= 1) s += __shfl_xor(s, o);
  if ((d & 63) == 0) red[d >> 6] = s;
  __syncthreads();
  float var = (red[0] + red[1] + red[2] + red[3]) * (1.f / 256.f);
  float y = g[d] * dv * rsqrtf(var + 1e-5f) + bb[d];
  h[b * 256 + d] = gelu_f(y);
}

// ---------------- router ----------------
__global__ __launch_bounds__(64) void k_router(const float* __restrict__ h,
    const float* __restrict__ rw, const float* __restrict__ eb,
    float* __restrict__ wts, int* __restrict__ idx,
    float* __restrict__ pm_sum, float* __restrict__ z_sum)
{
  int b = blockIdx.x, lane = threadIdx.x;
  float4 hv = *(const float4*)(h + b * 256 + lane * 4);
  float logit[8];
#pragma unroll
  for (int e = 0; e < 8; ++e) {
    float4 wv = *(const float4*)(rw + e * 256 + lane * 4);
    float p = hv.x * wv.x + hv.y * wv.y + hv.z * wv.z + hv.w * wv.w;
    for (int o = 32; o; o >>= 1) p += __shfl_xor(p, o);
    logit[e] = p + eb[e];
  }
  float mx = logit[0];
#pragma unroll
  for (int e = 1; e < 8; ++e) mx = fmaxf(mx, logit[e]);
  float pr[8]; float se = 0.f;
#pragma unroll
  for (int e = 0; e < 8; ++e) { pr[e] = expf(logit[e] - mx); se += pr[e]; }
  float inv = 1.f / se;
#pragma unroll
  for (int e = 0; e < 8; ++e) pr[e] *= inv;
  int i0 = 0; float v0 = pr[0];
#pragma unroll
  for (int e = 1; e < 8; ++e) if (pr[e] > v0) { v0 = pr[e]; i0 = e; }
  int i1 = -1; float v1 = -1.f;
#pragma unroll
  for (int e = 0; e < 8; ++e) if (e != i0 && pr[e] > v1) { v1 = pr[e]; i1 = e; }
  if (lane == 0) {
    float ssum = v0 + v1 + 1e-8f;
    wts[2 * b] = v0 / ssum; wts[2 * b + 1] = v1 / ssum;
    idx[2 * b] = i0; idx[2 * b + 1] = i1;
    float zz = 0.f;
#pragma unroll
    for (int e = 0; e < 8; ++e) zz += logit[e] * logit[e];
    atomicAdd(z_sum, zz);
  }
  if (lane < 8) atomicAdd(&pm_sum[lane], pr[lane]);
}

// ---------------- combine top-2 + 0.5*shared, then final LN ----------------
__global__ __launch_bounds__(256) void k_combine_ln(const float* __restrict__ eout,
    const float* __restrict__ sharedB, const float* __restrict__ wts, const int* __restrict__ idx,
    const float* __restrict__ g, const float* __restrict__ bb, float* __restrict__ out)
{
  int b = blockIdx.x, d = threadIdx.x;
  float w0 = wts[2 * b], w1 = wts[2 * b + 1];
  int i0 = idx[2 * b], i1 = idx[2 * b + 1];
  float val = w0 * eout[(long)i0 * 262144 + b * 256 + d]
            + w1 * eout[(long)i1 * 262144 + b * 256 + d]
            + 0.5f * sharedB[b * 256 + d];
  __shared__ float red[4];
  float s = val;
  for (int o = 32; o; o >>= 1) s += __shfl_xor(s, o);
  if ((d & 63) == 0) red[d >> 6] = s;
  __syncthreads();
  float mean = (red[0] + red[1] + red[2] + red[3]) * (1.f / 256.f);
  __syncthreads();
  float dv = val - mean;
  s = dv * dv;
  for (int o = 32; o; o >>= 1) s += __shfl_xor(s, o);
  if ((d & 63) == 0) red[d >> 6] = s;
  __syncthreads();
  float var = (red[0] + red[1] + red[2] + red[3]) * (1.f / 256.f);
  out[b * 256 + d] = g[d] * dv * rsqrtf(var + 1e-5f) + bb[d];
}

// ---------------- aux losses ----------------
__global__ void k_losses(const float* __restrict__ pm_sum, const float* __restrict__ z_sum,
                         float* __restrict__ out)
{
  if (threadIdx.x == 0 && blockIdx.x == 0) {
    float lb = 0.f;
    for (int e = 0; e < 8; ++e) {
      float pm = pm_sum[e] * (1.f / 1024.f);
      float dd = pm - 0.125f;
      lb += dd * dd;
    }
    out[262144] = lb * 8.f;
    out[262145] = z_sum[0] * (1.f / 8192.f) * 0.001f;
  }
}

extern "C" void kernel_launch(void* const* d_in, const int* in_sizes, int n_in,
                              void* d_out, int out_size, void* d_ws, size_t ws_size,
                              hipStream_t stream)
{
  const float* x     = (const float*)d_in[0];
  const float* c1w   = (const float*)d_in[1];
  const float* c1b   = (const float*)d_in[2];
  const float* bn1g  = (const float*)d_in[3];
  const float* bn1b  = (const float*)d_in[4];
  const float* c2w   = (const float*)d_in[5];
  const float* c2b   = (const float*)d_in[6];
  const float* bn2g  = (const float*)d_in[7];
  const float* bn2b  = (const float*)d_in[8];
  const float* c3w   = (const float*)d_in[9];
  const float* c3b   = (const float*)d_in[10];
  const float* bn3g  = (const float*)d_in[11];
  const float* bn3b  = (const float*)d_in[12];
  const float* projw = (const float*)d_in[13];
  const float* projb = (const float*)d_in[14];
  const float* lng   = (const float*)d_in[15];
  const float* lnb   = (const float*)d_in[16];
  const float* rw    = (const float*)d_in[17];
  const float* ebias = (const float*)d_in[18];
  const float* ew1   = (const float*)d_in[19];
  const float* eb1   = (const float*)d_in[20];
  const float* ew2   = (const float*)d_in[21];
  const float* eb2   = (const float*)d_in[22];
  const float* sw1   = (const float*)d_in[23];
  const float* sb1   = (const float*)d_in[24];
  const float* sw2   = (const float*)d_in[25];
  const float* sb2   = (const float*)d_in[26];
  const float* mlng  = (const float*)d_in[27];
  const float* mlnb  = (const float*)d_in[28];
  float* out = (float*)d_out;

  float* W = (float*)d_ws;
  float* y1    = W;                      // 44,728,320 floats (also y3 alias)
  float* y2    = W + 44728320L;          // 18,874,368
  float* hid   = W + 63602688L;          // 4,194,304
  float* eoutB = W + 67796992L;          // 2,097,152
  float* parts = W + 69894144L;          // 2,097,152 (8 x 262144)
  float* tbuf  = W + 71991296L;          // 262,144
  float* hbuf  = W + 72253440L;          // 262,144
  float* sh1   = W + 72515584L;          // 262,144
  float* shB   = W + 72777728L;          // 262,144
  float* stats = W + 73039872L;          // 1,024
  float* wtsb  = W + 73040896L;          // 2,048
  int*   idxb  = (int*)(W + 73042944L);  // 2,048
  float* wt1   = W + 73044992L;          // 8,192 (transposed conv1 weights)
  float* y3 = y1;

  float* sums1 = stats;        float* scale1 = stats + 512; float* shift1 = stats + 544;
  float* sums2 = stats + 64;   float* scale2 = stats + 576; float* shift2 = stats + 640;
  float* sums3 = stats + 192;  float* scale3 = stats + 704; float* shift3 = stats + 832;
  float* pm    = stats + 448;  float* zsum   = stats + 456;

  dim3 blk(256);
  k_zero<<<dim3(2), blk, 0, stream>>>(stats, 512);
  k_wt1<<<dim3(32), blk, 0, stream>>>(c1w, wt1);

  k_conv1<<<dim3(12, 1024), blk, 0, stream>>>(x, wt1, c1b, y1);
  k_bn_stats<<<dim3(32, 32), blk, 0, stream>>>(y1, sums1, 32, 1365, 32);
  k_bn_finalize<<<1, 32, 0, stream>>>(sums1, bn1g, bn1b, scale1, shift1, 32, 1.f / 1397760.f);
  k_bn_apply<<<dim3(32768), blk, 0, stream>>>(y1, scale1, shift1, 32, 1365);

  k_conv2<<<dim3(4, 1024), blk, 0, stream>>>(y1, c2w, c2b, y2);
  k_bn_stats<<<dim3(64, 16), blk, 0, stream>>>(y2, sums2, 64, 288, 64);
  k_bn_finalize<<<1, 64, 0, stream>>>(sums2, bn2g, bn2b, scale2, shift2, 64, 1.f / 294912.f);
  k_bn_apply<<<dim3(65536), blk, 0, stream>>>(y2, scale2, shift2, 64, 288);

  k_conv3<<<dim3(1024), blk, 0, stream>>>(y2, c3w, c3b, y3);
  k_bn_stats<<<dim3(128, 32), blk, 0, stream>>>(y3, sums3, 128, 224, 32);
  k_bn_finalize<<<1, 128, 0, stream>>>(sums3, bn3g, bn3b, scale3, shift3, 128, 1.f / 229376.f);
  k_bn_apply<<<dim3(131072), blk, 0, stream>>>(y3, scale3, shift3, 128, 224);

  // proj: [1024,28672] x [256,28672]^T, split-K=8
  k_gemm64<<<dim3(16, 4, 8), blk, 0, stream>>>(y3, 28672, projw, 28672, nullptr,
                                               parts, 256, 3584, 3584L, 3584L, 262144L, 0, 0);
  k_proj_reduce<<<dim3(1024), blk, 0, stream>>>(parts, projb, tbuf);
  k_ln_gelu<<<dim3(1024), blk, 0, stream>>>(tbuf, lng, lnb, hbuf);

  k_router<<<dim3(1024), dim3(64), 0, stream>>>(hbuf, rw, ebias, wtsb, idxb, pm, zsum);

  // dense experts
  k_gemm64<<<dim3(16, 8, 8), blk, 0, stream>>>(hbuf, 256, ew1, 256, eb1,
                                               hid, 512, 256, 0L, 131072L, 524288L, 512, 1);
  k_gemm64<<<dim3(16, 4, 8), blk, 0, stream>>>(hid, 512, ew2, 512, eb2,
                                               eoutB, 256, 512, 524288L, 131072L, 262144L, 256, 0);
  // shared expert
  k_gemm64<<<dim3(16, 4, 1), blk, 0, stream>>>(hbuf, 256, sw1, 256, sb1,
                                               sh1, 256, 256, 0L, 0L, 0L, 0, 1);
  k_gemm64<<<dim3(16, 4, 1), blk, 0, stream>>>(sh1, 256, sw2, 256, sb2,
                                               shB, 256, 256, 0L, 0L, 0L, 0, 0);

  k_combine_ln<<<dim3(1024), blk, 0, stream>>>(eoutB, shB, wtsb, idxb, mlng, mlnb, out);
  k_losses<<<1, 64, 0, stream>>>(pm, zsum, out);
}

// Round 4
// 1609.422 us; speedup vs baseline: 16.2303x; 2.0700x over previous
//
#include <hip/hip_runtime.h>
#include <hip/hip_bf16.h>
#include <math.h>

typedef unsigned short u16;
typedef unsigned int u32;
typedef __attribute__((ext_vector_type(8))) short bf16x8;
typedef __attribute__((ext_vector_type(4))) float f32x4;

#define DEV __device__ __forceinline__

DEV float gelu_f(float x) { return 0.5f * x * (1.0f + erff(x * 0.70710678118654752f)); }
DEV u16 f2bf(float f) { u32 u = __builtin_bit_cast(u32, f); u = (u + 0x7FFFu + ((u >> 16) & 1u)) >> 16; return (u16)u; }
DEV float bf2f(u16 h) { return __builtin_bit_cast(float, (u32)h << 16); }
DEV f32x4 mfma4(bf16x8 ah, bf16x8 al, bf16x8 bh, bf16x8 bl, f32x4 c) {
  c = __builtin_amdgcn_mfma_f32_16x16x32_bf16(ah, bh, c, 0, 0, 0);
  c = __builtin_amdgcn_mfma_f32_16x16x32_bf16(ah, bl, c, 0, 0, 0);
  c = __builtin_amdgcn_mfma_f32_16x16x32_bf16(al, bh, c, 0, 0, 0);
  c = __builtin_amdgcn_mfma_f32_16x16x32_bf16(al, bl, c, 0, 0, 0);
  return c;
}

// ---------------- zero stats ----------------
__global__ void k_zero(float* p, int n) {
  int i = blockIdx.x * blockDim.x + threadIdx.x;
  if (i < n) p[i] = 0.f;
}

// ---------------- weight frag preps: layout [((oct*NS + s)*64 + lane)*8 + j] ----------------
// conv1: k = kh*32 + kw*4 + c  (NS=8, 2 octiles)
__global__ void k_wprep1(const float* __restrict__ w, u16* __restrict__ wh, u16* __restrict__ wl) {
  int idx = blockIdx.x * 256 + threadIdx.x; if (idx >= 8192) return;
  int j = idx & 7, lane = (idx >> 3) & 63, s = (idx >> 9) & 7, oct = idx >> 12;
  int oc = oct * 16 + (lane & 15);
  int kl = ((lane >> 4) << 3) + j;
  int kw = kl >> 2, c = kl & 3, kh = s;
  float v = w[((oc * 4 + c) * 8 + kh) * 8 + kw];
  u16 h = f2bf(v); wh[idx] = h; wl[idx] = f2bf(v - bf2f(h));
}
// conv2: k = kh*128 + kw*32 + c (NS=16, 4 octiles)
__global__ void k_wprep2(const float* __restrict__ w, u16* __restrict__ wh, u16* __restrict__ wl) {
  int idx = blockIdx.x * 256 + threadIdx.x; if (idx >= 32768) return;
  int j = idx & 7, lane = (idx >> 3) & 63, s = (idx >> 9) & 15, oct = idx >> 13;
  int oc = oct * 16 + (lane & 15);
  int k = s * 32 + ((lane >> 4) << 3) + j;
  int kh = k >> 7, kw = (k >> 5) & 3, c = k & 31;
  float v = w[((oc * 32 + c) * 4 + kh) * 4 + kw];
  u16 h = f2bf(v); wh[idx] = h; wl[idx] = f2bf(v - bf2f(h));
}
// conv3: k = kh*192 + kw*64 + c (NS=18, 8 octiles)
__global__ void k_wprep3(const float* __restrict__ w, u16* __restrict__ wh, u16* __restrict__ wl) {
  int idx = blockIdx.x * 256 + threadIdx.x; if (idx >= 73728) return;
  int j = idx & 7, lane = (idx >> 3) & 63, rest = idx >> 9;
  int s = rest % 18, oct = rest / 18;
  int oc = oct * 16 + (lane & 15);
  int k = s * 32 + ((lane >> 4) << 3) + j;
  int kh = k / 192, r = k - kh * 192;
  int kw = r >> 6, c = r & 63;
  float v = w[((oc * 64 + c) * 3 + kh) * 3 + kw];
  u16 h = f2bf(v); wh[idx] = h; wl[idx] = f2bf(v - bf2f(h));
}
// proj: our k-order ks = pix*128 + oc3; ref kref = oc3*224 + pix (NS=896, 16 octiles)
__global__ void k_wprepP(const float* __restrict__ w, u16* __restrict__ wh, u16* __restrict__ wl) {
  int idx = blockIdx.x * 256 + threadIdx.x; if (idx >= 7340032) return;
  int j = idx & 7, lane = (idx >> 3) & 63, rest = idx >> 9;
  int ksg = rest % 896, oct = rest / 896;
  int n = oct * 16 + (lane & 15);
  int ks = ksg * 32 + ((lane >> 4) << 3) + j;
  int kref = (ks & 127) * 224 + (ks >> 7);
  float v = w[(long)n * 28672 + kref];
  u16 h = f2bf(v); wh[idx] = h; wl[idx] = f2bf(v - bf2f(h));
}

// ---------------- conv1 MFMA: x[1024,4,144,160] s4 8x8 -> y1[1024][1365 pix][32 oc] hi/lo
__global__ __launch_bounds__(256) void k_conv1m(const float* __restrict__ x,
    const u16* __restrict__ wfh, const u16* __restrict__ wfl,
    const float* __restrict__ bias, u16* __restrict__ outh, u16* __restrict__ outl)
{
  __shared__ __align__(16) u16 sin0[7680], sin1[7680];   // [12 rows][160 cols][4 c]
  __shared__ __align__(16) u16 swf0[8192], swf1[8192];   // both octiles
  int ohp = blockIdx.x, b = blockIdx.y, tid = threadIdx.x;
  int row0 = ohp * 8;
  // stage input rows row0..row0+11, transposed ch-last, split hi/lo (2 c per thread-elem)
  for (int i = tid; i < 3840; i += 256) {
    int cp = i / 1920, jr = i - cp * 1920;
    int r = jr / 160, col = jr - r * 160;
    int grow = row0 + r;
    float v0 = 0.f, v1 = 0.f;
    if (grow < 144) {
      long base = ((long)b * 4 + 2 * cp) * 23040 + (long)grow * 160 + col;
      v0 = x[base]; v1 = x[base + 23040];
    }
    u16 h0 = f2bf(v0), h1 = f2bf(v1);
    u16 l0 = f2bf(v0 - bf2f(h0)), l1 = f2bf(v1 - bf2f(h1));
    ((u32*)sin0)[r * 320 + col * 2 + cp] = (u32)h0 | ((u32)h1 << 16);
    ((u32*)sin1)[r * 320 + col * 2 + cp] = (u32)l0 | ((u32)l1 << 16);
  }
  for (int i = tid; i < 1024; i += 256) {
    ((uint4*)swf0)[i] = ((const uint4*)wfh)[i];
    ((uint4*)swf1)[i] = ((const uint4*)wfl)[i];
  }
  __syncthreads();
  int w = tid >> 6, lane = tid & 63, g = lane >> 4, ln = lane & 15;
  // jobs: j = w (+4): ohl = j/3, owt = j%3
  int ohls[2], owcs[2];
  {
    int j0 = w;          ohls[0] = j0 / 3; owcs[0] = (j0 % 3) * 16 + ln; if (owcs[0] > 38) owcs[0] = 38;
    int j1 = w + 4;      int oh1 = j1 / 3, ow1 = (j1 % 3) * 16 + ln; if (ow1 > 38) ow1 = 38;
    ohls[1] = (j1 < 6) ? oh1 : 0; owcs[1] = (j1 < 6) ? ow1 : 0;
  }
  f32x4 z4 = {0.f, 0.f, 0.f, 0.f};
  f32x4 acc[2][2];
  acc[0][0] = z4; acc[0][1] = z4; acc[1][0] = z4; acc[1][1] = z4;
#pragma unroll
  for (int kh = 0; kh < 8; ++kh) {
    bf16x8 bh0 = *(const bf16x8*)&swf0[kh * 512 + lane * 8];
    bf16x8 bl0 = *(const bf16x8*)&swf1[kh * 512 + lane * 8];
    bf16x8 bh1 = *(const bf16x8*)&swf0[4096 + kh * 512 + lane * 8];
    bf16x8 bl1 = *(const bf16x8*)&swf1[4096 + kh * 512 + lane * 8];
#pragma unroll
    for (int jj = 0; jj < 2; ++jj) {
      if (jj == 1 && w >= 2) continue;
      int off = (4 * ohls[jj] + kh) * 640 + owcs[jj] * 16 + g * 8;
      bf16x8 ah = *(const bf16x8*)&sin0[off];
      bf16x8 al = *(const bf16x8*)&sin1[off];
      acc[jj][0] = mfma4(ah, al, bh0, bl0, acc[jj][0]);
      acc[jj][1] = mfma4(ah, al, bh1, bl1, acc[jj][1]);
    }
  }
#pragma unroll
  for (int jj = 0; jj < 2; ++jj) {
    if (jj == 1 && w >= 2) continue;
    int j = w + jj * 4;
    int ohl = j / 3, owt = j % 3;
    int oh = 2 * ohp + ohl;
    if (oh >= 35) continue;
#pragma unroll
    for (int oct = 0; oct < 2; ++oct) {
      int oc = oct * 16 + ln;
      float bv = bias[oc];
#pragma unroll
      for (int r = 0; r < 4; ++r) {
        int owo = owt * 16 + g * 4 + r;
        if (owo < 39) {
          long oi = ((long)b * 1365 + oh * 39 + owo) * 32 + oc;
          float v = acc[jj][oct][r] + bv;
          u16 hv = f2bf(v);
          outh[oi] = hv; outl[oi] = f2bf(v - bf2f(hv));
        }
      }
    }
  }
}

// ---------------- conv2 MFMA: y1a[1024][1365][32] s2 4x4 -> y2[1024][288][64]
__global__ __launch_bounds__(256) void k_conv2m(const u16* __restrict__ inh, const u16* __restrict__ inl,
    const u16* __restrict__ wfh, const u16* __restrict__ wfl,
    const float* __restrict__ bias, u16* __restrict__ outh, u16* __restrict__ outl)
{
  __shared__ __align__(16) u16 sin0[12480], sin1[12480];  // [10 rows][39 cols][32 c]
  __shared__ __align__(16) u16 swf0[4096], swf1[4096];    // 1 octile, 8 ksteps
  int ohq = blockIdx.x, b = blockIdx.y, tid = threadIdx.x;
  long sb = ((long)b * 1365 + (long)ohq * 8 * 39) * 32;
  const uint4* s0 = (const uint4*)(inh + sb);
  const uint4* s1 = (const uint4*)(inl + sb);
  for (int i = tid; i < 1560; i += 256) { ((uint4*)sin0)[i] = s0[i]; ((uint4*)sin1)[i] = s1[i]; }
  int w = tid >> 6, lane = tid & 63, g = lane >> 4, ln = lane & 15;
  int rowb[2], colb[2];
#pragma unroll
  for (int jj = 0; jj < 2; ++jj) {
    int pt = jj ? 4 : w;
    int p = pt * 16 + ln; if (p > 71) p = 71;
    int ohl = p / 18, ow = p - 18 * ohl;
    rowb[jj] = 2 * ohl; colb[jj] = 2 * ow;
  }
  for (int oct = 0; oct < 4; ++oct) {
    f32x4 z4 = {0.f, 0.f, 0.f, 0.f};
    f32x4 acc[2]; acc[0] = z4; acc[1] = z4;
    for (int khh = 0; khh < 2; ++khh) {
      __syncthreads();
      const uint4* w0 = (const uint4*)(wfh + oct * 8192 + khh * 4096);
      const uint4* w1 = (const uint4*)(wfl + oct * 8192 + khh * 4096);
      for (int i = tid; i < 512; i += 256) { ((uint4*)swf0)[i] = w0[i]; ((uint4*)swf1)[i] = w1[i]; }
      __syncthreads();
#pragma unroll
      for (int sl = 0; sl < 8; ++sl) {
        int s = khh * 8 + sl;
        int kh = s >> 2, kw = s & 3;
        bf16x8 bh = *(const bf16x8*)&swf0[sl * 512 + lane * 8];
        bf16x8 bl = *(const bf16x8*)&swf1[sl * 512 + lane * 8];
#pragma unroll
        for (int jj = 0; jj < 2; ++jj) {
          if (jj == 1 && w != 0) continue;
          int off = (rowb[jj] + kh) * 1248 + (colb[jj] + kw) * 32 + g * 8;
          bf16x8 ah = *(const bf16x8*)&sin0[off];
          bf16x8 al = *(const bf16x8*)&sin1[off];
          acc[jj] = mfma4(ah, al, bh, bl, acc[jj]);
        }
      }
    }
    int oc = oct * 16 + ln;
    float bv = bias[oc];
#pragma unroll
    for (int jj = 0; jj < 2; ++jj) {
      if (jj == 1 && w != 0) continue;
      int pt = jj ? 4 : w;
#pragma unroll
      for (int r = 0; r < 4; ++r) {
        int po = pt * 16 + g * 4 + r;
        if (po < 72) {
          long oi = ((long)b * 288 + (long)ohq * 72 + po) * 64 + oc;
          float v = acc[jj][r] + bv;
          u16 hv = f2bf(v);
          outh[oi] = hv; outl[oi] = f2bf(v - bf2f(hv));
        }
      }
    }
  }
}

// ---------------- conv3 MFMA: y2a[1024][288][64] s1 3x3 -> y3[1024][224][128]
__global__ __launch_bounds__(256) void k_conv3m(const u16* __restrict__ inh, const u16* __restrict__ inl,
    const u16* __restrict__ wfh, const u16* __restrict__ wfl,
    const float* __restrict__ bias, u16* __restrict__ outh, u16* __restrict__ outl)
{
  __shared__ __align__(16) u16 sin0[10368], sin1[10368];  // [9 rows][18 cols][64 c]
  __shared__ __align__(16) u16 swf0[9216], swf1[9216];    // 1 octile, 18 ksteps
  int hh = blockIdx.x, b = blockIdx.y, tid = threadIdx.x;
  long sb = ((long)b * 288 + (long)hh * 126) * 64;
  const uint4* s0 = (const uint4*)(inh + sb);
  const uint4* s1 = (const uint4*)(inl + sb);
  for (int i = tid; i < 1296; i += 256) { ((uint4*)sin0)[i] = s0[i]; ((uint4*)sin1)[i] = s1[i]; }
  int w = tid >> 6, lane = tid & 63, g = lane >> 4, ln = lane & 15;
  for (int oct = 0; oct < 8; ++oct) {
    __syncthreads();
    const uint4* w0 = (const uint4*)(wfh + oct * 9216);
    const uint4* w1 = (const uint4*)(wfl + oct * 9216);
    for (int i = tid; i < 1152; i += 256) { ((uint4*)swf0)[i] = w0[i]; ((uint4*)swf1)[i] = w1[i]; }
    __syncthreads();
    f32x4 z4 = {0.f, 0.f, 0.f, 0.f};
    f32x4 acc[2]; acc[0] = z4; acc[1] = z4;
#pragma unroll
    for (int s = 0; s < 18; ++s) {
      const int kh = s / 6, rm = s % 6;
      const int kw = rm >> 1, ch = rm & 1;
      bf16x8 bh = *(const bf16x8*)&swf0[s * 512 + lane * 8];
      bf16x8 bl = *(const bf16x8*)&swf1[s * 512 + lane * 8];
#pragma unroll
      for (int jj = 0; jj < 2; ++jj) {
        if (jj == 1 && w == 3) continue;
        int ohl = w + jj * 4;
        int off = ((ohl + kh) * 18 + ln + kw) * 64 + ch * 32 + g * 8;
        bf16x8 ah = *(const bf16x8*)&sin0[off];
        bf16x8 al = *(const bf16x8*)&sin1[off];
        acc[jj] = mfma4(ah, al, bh, bl, acc[jj]);
      }
    }
    int oc = oct * 16 + ln;
    float bv = bias[oc];
#pragma unroll
    for (int jj = 0; jj < 2; ++jj) {
      if (jj == 1 && w == 3) continue;
      int ohl = w + jj * 4;
#pragma unroll
      for (int r = 0; r < 4; ++r) {
        int owo = g * 4 + r;
        long oi = ((long)b * 224 + (hh * 7 + ohl) * 16 + owo) * 128 + oc;
        float v = acc[jj][r] + bv;
        u16 hv = f2bf(v);
        outh[oi] = hv; outl[oi] = f2bf(v - bf2f(hv));
      }
    }
  }
}

// ---------------- BN stats over channels-last hi/lo ----------------
__global__ __launch_bounds__(256) void k_bnstat(const u16* __restrict__ h, const u16* __restrict__ l,
    float* __restrict__ sums, int C, long npix)
{
  int half = C >> 1;
  int cp = threadIdx.x % half;
  int rl = threadIdx.x / half;
  int rpi = 256 / half;
  long chunk = (npix + gridDim.x - 1) / gridDim.x;
  long p0 = (long)blockIdx.x * chunk;
  long p1 = p0 + chunk; if (p1 > npix) p1 = npix;
  float s1a = 0.f, s1b = 0.f, s2a = 0.f, s2b = 0.f;
  for (long p = p0 + rl; p < p1; p += rpi) {
    u32 hu = *(const u32*)(h + p * C + cp * 2);
    u32 lu = *(const u32*)(l + p * C + cp * 2);
    float v0 = bf2f((u16)(hu & 0xFFFF)) + bf2f((u16)(lu & 0xFFFF));
    float v1 = bf2f((u16)(hu >> 16)) + bf2f((u16)(lu >> 16));
    s1a += v0; s2a += v0 * v0; s1b += v1; s2b += v1 * v1;
  }
  __shared__ float bs1[128], bs2[128];
  for (int i = threadIdx.x; i < C; i += 256) { bs1[i] = 0.f; bs2[i] = 0.f; }
  __syncthreads();
  atomicAdd(&bs1[2 * cp], s1a); atomicAdd(&bs1[2 * cp + 1], s1b);
  atomicAdd(&bs2[2 * cp], s2a); atomicAdd(&bs2[2 * cp + 1], s2b);
  __syncthreads();
  if (threadIdx.x < C) {
    atomicAdd(&sums[threadIdx.x], bs1[threadIdx.x]);
    atomicAdd(&sums[C + threadIdx.x], bs2[threadIdx.x]);
  }
}

__global__ void k_bn_finalize(const float* __restrict__ sums, const float* __restrict__ g,
    const float* __restrict__ b, float* __restrict__ scale, float* __restrict__ shift,
    int C, float invN)
{
  int c = threadIdx.x;
  if (c < C) {
    float m = sums[c] * invN;
    float var = sums[C + c] * invN - m * m;
    float sc = g[c] * rsqrtf(var + 1e-5f);
    scale[c] = sc;
    shift[c] = b[c] - m * sc;
  }
}

// ---------------- BN apply + GELU, in-place on hi/lo ch-last ----------------
__global__ __launch_bounds__(256) void k_bnapply(u16* __restrict__ h, u16* __restrict__ l,
    const float* __restrict__ scale, const float* __restrict__ shift, int C, long nelem)
{
  __shared__ float sc[128], sh[128];
  for (int i = threadIdx.x; i < C; i += 256) { sc[i] = scale[i]; sh[i] = shift[i]; }
  __syncthreads();
  long i0 = ((long)blockIdx.x * 256 + threadIdx.x) * 4;
  long stride = (long)gridDim.x * 1024;
  for (long i = i0; i < nelem; i += stride) {
    uint2 hu = *(uint2*)(h + i);
    uint2 lu = *(uint2*)(l + i);
    int cb = (int)(i & (long)(C - 1));
    u16 hs[4] = { (u16)(hu.x & 0xFFFF), (u16)(hu.x >> 16), (u16)(hu.y & 0xFFFF), (u16)(hu.y >> 16) };
    u16 ls[4] = { (u16)(lu.x & 0xFFFF), (u16)(lu.x >> 16), (u16)(lu.y & 0xFFFF), (u16)(lu.y >> 16) };
    u16 nh[4], nl[4];
#pragma unroll
    for (int j = 0; j < 4; ++j) {
      float v = bf2f(hs[j]) + bf2f(ls[j]);
      float a = gelu_f(v * sc[cb + j] + sh[cb + j]);
      nh[j] = f2bf(a);
      nl[j] = f2bf(a - bf2f(nh[j]));
    }
    uint2 ho, lo;
    ho.x = (u32)nh[0] | ((u32)nh[1] << 16); ho.y = (u32)nh[2] | ((u32)nh[3] << 16);
    lo.x = (u32)nl[0] | ((u32)nl[1] << 16); lo.y = (u32)nl[2] | ((u32)nl[3] << 16);
    *(uint2*)(h + i) = ho;
    *(uint2*)(l + i) = lo;
  }
}

// ---------------- proj MFMA split-K: [1024 tok x 28672] x [256 x 28672]^T -> part[32][1024][256]
__global__ __launch_bounds__(256) void k_projm(const u16* __restrict__ ah_g, const u16* __restrict__ al_g,
    const u16* __restrict__ bh_g, const u16* __restrict__ bl_g, float* __restrict__ part)
{
  __shared__ __align__(16) u16 Ah[4096], Al[4096];   // [128 tok][32 k]
  __shared__ __align__(16) u16 Bh[8192], Bl[8192];   // [16 oct][512]
  int m0 = blockIdx.x * 128, by = blockIdx.y, tid = threadIdx.x;
  int w = tid >> 6, lane = tid & 63, g = lane >> 4, ln = lane & 15;
  f32x4 z4 = {0.f, 0.f, 0.f, 0.f};
  f32x4 acc[2][16];
#pragma unroll
  for (int p = 0; p < 2; ++p)
#pragma unroll
    for (int o = 0; o < 16; ++o) acc[p][o] = z4;
  for (int ks = 0; ks < 28; ++ks) {
    __syncthreads();
    long k0 = ((long)by * 28 + ks) * 32;
    for (int i = tid; i < 512; i += 256) {
      int row = i >> 2, q = i & 3;
      ((uint4*)Ah)[i] = *((const uint4*)(ah_g + (long)(m0 + row) * 28672 + k0) + q);
      ((uint4*)Al)[i] = *((const uint4*)(al_g + (long)(m0 + row) * 28672 + k0) + q);
    }
    int ksg = by * 28 + ks;
    for (int i = tid; i < 1024; i += 256) {
      int oct = i >> 6, r2 = i & 63;
      ((uint4*)Bh)[i] = *((const uint4*)(bh_g + ((long)oct * 896 + ksg) * 512) + r2);
      ((uint4*)Bl)[i] = *((const uint4*)(bl_g + ((long)oct * 896 + ksg) * 512) + r2);
    }
    __syncthreads();
    bf16x8 ah[2], al[2];
#pragma unroll
    for (int pt = 0; pt < 2; ++pt) {
      int off = ((2 * w + pt) * 16 + ln) * 32 + g * 8;
      ah[pt] = *(const bf16x8*)&Ah[off];
      al[pt] = *(const bf16x8*)&Al[off];
    }
#pragma unroll
    for (int oct = 0; oct < 16; ++oct) {
      bf16x8 bh = *(const bf16x8*)&Bh[oct * 512 + lane * 8];
      bf16x8 bl = *(const bf16x8*)&Bl[oct * 512 + lane * 8];
#pragma unroll
      for (int pt = 0; pt < 2; ++pt)
        acc[pt][oct] = mfma4(ah[pt], al[pt], bh, bl, acc[pt][oct]);
    }
  }
#pragma unroll
  for (int pt = 0; pt < 2; ++pt)
#pragma unroll
    for (int oct = 0; oct < 16; ++oct) {
      int oc = oct * 16 + ln;
#pragma unroll
      for (int r = 0; r < 4; ++r) {
        int tok = m0 + (2 * w + pt) * 16 + g * 4 + r;
        part[((long)by * 1024 + tok) * 256 + oc] = acc[pt][oct][r];
      }
    }
}

// ---------------- split-K reduce + bias + LN + GELU ----------------
__global__ __launch_bounds__(256) void k_lnred(const float* __restrict__ part,
    const float* __restrict__ pb, const float* __restrict__ g, const float* __restrict__ be,
    float* __restrict__ h)
{
  int b = blockIdx.x, d = threadIdx.x;
  float s = pb[d];
#pragma unroll
  for (int ks = 0; ks < 32; ++ks) s += part[((long)ks * 1024 + b) * 256 + d];
  __shared__ float red[4];
  float t = s;
  for (int o = 32; o; o >>= 1) t += __shfl_xor(t, o);
  if ((d & 63) == 0) red[d >> 6] = t;
  __syncthreads();
  float mean = (red[0] + red[1] + red[2] + red[3]) * (1.f / 256.f);
  __syncthreads();
  float dv = s - mean;
  t = dv * dv;
  for (int o = 32; o; o >>= 1) t += __shfl_xor(t, o);
  if ((d & 63) == 0) red[d >> 6] = t;
  __syncthreads();
  float var = (red[0] + red[1] + red[2] + red[3]) * (1.f / 256.f);
  h[b * 256 + d] = gelu_f(g[d] * dv * rsqrtf(var + 1e-5f) + be[d]);
}

// ---------------- generic fp32 GEMM (experts/shared) ----------------
__global__ __launch_bounds__(256) void k_gemm64(const float* __restrict__ A, int lda,
    const float* __restrict__ B, int ldb, const float* __restrict__ bias,
    float* __restrict__ C, int ldc, int K,
    long aZ, long bZ, long cZ, int biasZ, int act)
{
  int z = blockIdx.z;
  A += (long)z * aZ; B += (long)z * bZ; C += (long)z * cZ;
  int m0 = blockIdx.x * 64, n0 = blockIdx.y * 64, tid = threadIdx.x;
  int tx = tid & 15, ty = tid >> 4;
  __shared__ float As[32][68], Bs[32][68];
  float acc[4][4] = {};
  for (int kt = 0; kt < K; kt += 32) {
#pragma unroll
    for (int s = 0; s < 2; ++s) {
      int t = tid + s * 256;
      int row = t >> 3, kq = (t & 7) * 4;
      float4 av = *(const float4*)(A + (long)(m0 + row) * lda + kt + kq);
      As[kq + 0][row] = av.x; As[kq + 1][row] = av.y; As[kq + 2][row] = av.z; As[kq + 3][row] = av.w;
      float4 bvv = *(const float4*)(B + (long)(n0 + row) * ldb + kt + kq);
      Bs[kq + 0][row] = bvv.x; Bs[kq + 1][row] = bvv.y; Bs[kq + 2][row] = bvv.z; Bs[kq + 3][row] = bvv.w;
    }
    __syncthreads();
#pragma unroll
    for (int kk = 0; kk < 32; ++kk) {
      float4 a4 = *(const float4*)&As[kk][ty * 4];
      float4 b4 = *(const float4*)&Bs[kk][tx * 4];
      acc[0][0] += a4.x * b4.x; acc[0][1] += a4.x * b4.y; acc[0][2] += a4.x * b4.z; acc[0][3] += a4.x * b4.w;
      acc[1][0] += a4.y * b4.x; acc[1][1] += a4.y * b4.y; acc[1][2] += a4.y * b4.z; acc[1][3] += a4.y * b4.w;
      acc[2][0] += a4.z * b4.x; acc[2][1] += a4.z * b4.y; acc[2][2] += a4.z * b4.z; acc[2][3] += a4.z * b4.w;
      acc[3][0] += a4.w * b4.x; acc[3][1] += a4.w * b4.y; acc[3][2] += a4.w * b4.z; acc[3][3] += a4.w * b4.w;
    }
    __syncthreads();
  }
  float bv[4] = {0.f, 0.f, 0.f, 0.f};
  if (bias) {
    const float* bp = bias + (long)z * biasZ + n0 + tx * 4;
    bv[0] = bp[0]; bv[1] = bp[1]; bv[2] = bp[2]; bv[3] = bp[3];
  }
  for (int i = 0; i < 4; ++i) {
    float* op = C + (long)(m0 + ty * 4 + i) * ldc + n0 + tx * 4;
    float4 o;
    o.x = acc[i][0] + bv[0]; o.y = acc[i][1] + bv[1];
    o.z = acc[i][2] + bv[2]; o.w = acc[i][3] + bv[3];
    if (act) { o.x = gelu_f(o.x); o.y = gelu_f(o.y); o.z = gelu_f(o.z); o.w = gelu_f(o.w); }
    *(float4*)op = o;
  }
}

// ---------------- router ----------------
__global__ __launch_bounds__(64) void k_router(const float* __restrict__ h,
    const float* __restrict__ rw, const float* __restrict__ eb,
    float* __restrict__ wts, int* __restrict__ idx,
    float* __restrict__ pm_sum, float* __restrict__ z_sum)
{
  int b = blockIdx.x, lane = threadIdx.x;
  float4 hv = *(const float4*)(h + b * 256 + lane * 4);
  float logit[8];
#pragma unroll
  for (int e = 0; e < 8; ++e) {
    float4 wv = *(const float4*)(rw + e * 256 + lane * 4);
    float p = hv.x * wv.x + hv.y * wv.y + hv.z * wv.z + hv.w * wv.w;
    for (int o = 32; o; o >>= 1) p += __shfl_xor(p, o);
    logit[e] = p + eb[e];
  }
  float mx = logit[0];
#pragma unroll
  for (int e = 1; e < 8; ++e) mx = fmaxf(mx, logit[e]);
  float pr[8]; float se = 0.f;
#pragma unroll
  for (int e = 0; e < 8; ++e) { pr[e] = expf(logit[e] - mx); se += pr[e]; }
  float inv = 1.f / se;
#pragma unroll
  for (int e = 0; e < 8; ++e) pr[e] *= inv;
  int i0 = 0; float v0 = pr[0];
#pragma unroll
  for (int e = 1; e < 8; ++e) if (pr[e] > v0) { v0 = pr[e]; i0 = e; }
  int i1 = -1; float v1 = -1.f;
#pragma unroll
  for (int e = 0; e < 8; ++e) if (e != i0 && pr[e] > v1) { v1 = pr[e]; i1 = e; }
  if (lane == 0) {
    float ssum = v0 + v1 + 1e-8f;
    wts[2 * b] = v0 / ssum; wts[2 * b + 1] = v1 / ssum;
    idx[2 * b] = i0; idx[2 * b + 1] = i1;
    float zz = 0.f;
#pragma unroll
    for (int e = 0; e < 8; ++e) zz += logit[e] * logit[e];
    atomicAdd(z_sum, zz);
  }
  if (lane < 8) atomicAdd(&pm_sum[lane], pr[lane]);
}

// ---------------- combine + 0.5*shared + final LN ----------------
__global__ __launch_bounds__(256) void k_combine_ln(const float* __restrict__ eout,
    const float* __restrict__ sharedB, const float* __restrict__ wts, const int* __restrict__ idx,
    const float* __restrict__ g, const float* __restrict__ bb, float* __restrict__ out)
{
  int b = blockIdx.x, d = threadIdx.x;
  float w0 = wts[2 * b], w1 = wts[2 * b + 1];
  int i0 = idx[2 * b], i1 = idx[2 * b + 1];
  float val = w0 * eout[(long)i0 * 262144 + b * 256 + d]
            + w1 * eout[(long)i1 * 262144 + b * 256 + d]
            + 0.5f * sharedB[b * 256 + d];
  __shared__ float red[4];
  float s = val;
  for (int o = 32; o; o >>= 1) s += __shfl_xor(s, o);
  if ((d & 63) == 0) red[d >> 6] = s;
  __syncthreads();
  float mean = (red[0] + red[1] + red[2] + red[3]) * (1.f / 256.f);
  __syncthreads();
  float dv = val - mean;
  s = dv * dv;
  for (int o = 32; o; o >>= 1) s += __shfl_xor(s, o);
  if ((d & 63) == 0) red[d >> 6] = s;
  __syncthreads();
  float var = (red[0] + red[1] + red[2] + red[3]) * (1.f / 256.f);
  out[b * 256 + d] = g[d] * dv * rsqrtf(var + 1e-5f) + bb[d];
}

// ---------------- aux losses ----------------
__global__ void k_losses(const float* __restrict__ pm_sum, const float* __restrict__ z_sum,
                         float* __restrict__ out)
{
  if (threadIdx.x == 0 && blockIdx.x == 0) {
    float lb = 0.f;
    for (int e = 0; e < 8; ++e) {
      float pm = pm_sum[e] * (1.f / 1024.f);
      float dd = pm - 0.125f;
      lb += dd * dd;
    }
    out[262144] = lb * 8.f;
    out[262145] = z_sum[0] * (1.f / 8192.f) * 0.001f;
  }
}

extern "C" void kernel_launch(void* const* d_in, const int* in_sizes, int n_in,
                              void* d_out, int out_size, void* d_ws, size_t ws_size,
                              hipStream_t stream)
{
  const float* x     = (const float*)d_in[0];
  const float* c1w   = (const float*)d_in[1];
  const float* c1b   = (const float*)d_in[2];
  const float* bn1g  = (const float*)d_in[3];
  const float* bn1b  = (const float*)d_in[4];
  const float* c2w   = (const float*)d_in[5];
  const float* c2b   = (const float*)d_in[6];
  const float* bn2g  = (const float*)d_in[7];
  const float* bn2b  = (const float*)d_in[8];
  const float* c3w   = (const float*)d_in[9];
  const float* c3b   = (const float*)d_in[10];
  const float* bn3g  = (const float*)d_in[11];
  const float* bn3b  = (const float*)d_in[12];
  const float* projw = (const float*)d_in[13];
  const float* projb = (const float*)d_in[14];
  const float* lng   = (const float*)d_in[15];
  const float* lnb   = (const float*)d_in[16];
  const float* rw    = (const float*)d_in[17];
  const float* ebias = (const float*)d_in[18];
  const float* ew1   = (const float*)d_in[19];
  const float* eb1   = (const float*)d_in[20];
  const float* ew2   = (const float*)d_in[21];
  const float* eb2   = (const float*)d_in[22];
  const float* sw1   = (const float*)d_in[23];
  const float* sb1   = (const float*)d_in[24];
  const float* sw2   = (const float*)d_in[25];
  const float* sb2   = (const float*)d_in[26];
  const float* mlng  = (const float*)d_in[27];
  const float* mlnb  = (const float*)d_in[28];
  float* out = (float*)d_out;

  char* W = (char*)d_ws;
  u16* y1h = (u16*)(W + 0);             // 89,456,640
  u16* y1l = (u16*)(W + 89456640L);
  u16* y2h = (u16*)(W + 178913280L);    // 37,748,736
  u16* y2l = (u16*)(W + 216662016L);
  u16* y3h = (u16*)(W + 0);             // alias dead y1 region
  u16* y3l = (u16*)(W + 58720256L);
  u16* wfph = (u16*)(W + 254410752L);   // 14,680,064
  u16* wfpl = (u16*)(W + 269090816L);
  u16* wf1h = (u16*)(W + 283770880L);
  u16* wf1l = (u16*)(W + 283787264L);
  u16* wf2h = (u16*)(W + 283803648L);
  u16* wf2l = (u16*)(W + 283869184L);
  u16* wf3h = (u16*)(W + 283934720L);
  u16* wf3l = (u16*)(W + 284082176L);
  float* stats = (float*)(W + 284229632L);
  float* wtsb  = (float*)(W + 284233728L);
  int*   idxb  = (int*)(W + 284241920L);
  float* hbuf  = (float*)(W + 284250112L);
  float* sh1   = (float*)(W + 285298688L);
  float* shB   = (float*)(W + 286347264L);
  float* part  = (float*)(W + 178913280L);  // alias y2 region (dead by proj time)
  float* hid   = (float*)(W + 178913280L);  // alias after part consumed
  float* eoutB = (float*)(W + 195690496L);

  float* sums1 = stats;        float* scale1 = stats + 512; float* shift1 = stats + 544;
  float* sums2 = stats + 64;   float* scale2 = stats + 576; float* shift2 = stats + 640;
  float* sums3 = stats + 192;  float* scale3 = stats + 704; float* shift3 = stats + 832;
  float* pm    = stats + 448;  float* zsum   = stats + 456;

  dim3 blk(256);
  k_zero<<<dim3(2), blk, 0, stream>>>(stats, 512);
  k_wprep1<<<dim3(32), blk, 0, stream>>>(c1w, wf1h, wf1l);
  k_wprep2<<<dim3(128), blk, 0, stream>>>(c2w, wf2h, wf2l);
  k_wprep3<<<dim3(288), blk, 0, stream>>>(c3w, wf3h, wf3l);
  k_wprepP<<<dim3(28672), blk, 0, stream>>>(projw, wfph, wfpl);

  k_conv1m<<<dim3(18, 1024), blk, 0, stream>>>(x, wf1h, wf1l, c1b, y1h, y1l);
  k_bnstat<<<dim3(512), blk, 0, stream>>>(y1h, y1l, sums1, 32, 1397760L);
  k_bn_finalize<<<1, 32, 0, stream>>>(sums1, bn1g, bn1b, scale1, shift1, 32, 1.f / 1397760.f);
  k_bnapply<<<dim3(2048), blk, 0, stream>>>(y1h, y1l, scale1, shift1, 32, 44728320L);

  k_conv2m<<<dim3(4, 1024), blk, 0, stream>>>(y1h, y1l, wf2h, wf2l, c2b, y2h, y2l);
  k_bnstat<<<dim3(512), blk, 0, stream>>>(y2h, y2l, sums2, 64, 294912L);
  k_bn_finalize<<<1, 64, 0, stream>>>(sums2, bn2g, bn2b, scale2, shift2, 64, 1.f / 294912.f);
  k_bnapply<<<dim3(2048), blk, 0, stream>>>(y2h, y2l, scale2, shift2, 64, 18874368L);

  k_conv3m<<<dim3(2, 1024), blk, 0, stream>>>(y2h, y2l, wf3h, wf3l, c3b, y3h, y3l);
  k_bnstat<<<dim3(512), blk, 0, stream>>>(y3h, y3l, sums3, 128, 229376L);
  k_bn_finalize<<<1, 128, 0, stream>>>(sums3, bn3g, bn3b, scale3, shift3, 128, 1.f / 229376.f);
  k_bnapply<<<dim3(2048), blk, 0, stream>>>(y3h, y3l, scale3, shift3, 128, 29360128L);

  k_projm<<<dim3(8, 32), blk, 0, stream>>>(y3h, y3l, wfph, wfpl, part);
  k_lnred<<<dim3(1024), blk, 0, stream>>>(part, projb, lng, lnb, hbuf);

  k_router<<<dim3(1024), dim3(64), 0, stream>>>(hbuf, rw, ebias, wtsb, idxb, pm, zsum);

  k_gemm64<<<dim3(16, 8, 8), blk, 0, stream>>>(hbuf, 256, ew1, 256, eb1,
                                               hid, 512, 256, 0L, 131072L, 524288L, 512, 1);
  k_gemm64<<<dim3(16, 4, 8), blk, 0, stream>>>(hid, 512, ew2, 512, eb2,
                                               eoutB, 256, 512, 524288L, 131072L, 262144L, 256, 0);
  k_gemm64<<<dim3(16, 4, 1), blk, 0, stream>>>(hbuf, 256, sw1, 256, sb1,
                                               sh1, 256, 256, 0L, 0L, 0L, 0, 1);
  k_gemm64<<<dim3(16, 4, 1), blk, 0, stream>>>(sh1, 256, sw2, 256, sb2,
                                               shB, 256, 256, 0L, 0L, 0L, 0, 0);

  k_combine_ln<<<dim3(1024), blk, 0, stream>>>(eoutB, shB, wtsb, idxb, mlng, mlnb, out);
  k_losses<<<1, 64, 0, stream>>>(pm, zsum, out);
}

// Round 5
// 1489.108 us; speedup vs baseline: 17.5416x; 1.0808x over previous
//
#include <hip/hip_runtime.h>
#include <hip/hip_bf16.h>
#include <math.h>

typedef unsigned short u16;
typedef unsigned int u32;
typedef __attribute__((ext_vector_type(8))) short bf16x8;
typedef __attribute__((ext_vector_type(4))) float f32x4;

#define DEV __device__ __forceinline__

DEV float gelu_f(float x) { return 0.5f * x * (1.0f + erff(x * 0.70710678118654752f)); }
DEV u16 f2bf(float f) { u32 u = __builtin_bit_cast(u32, f); u = (u + 0x7FFFu + ((u >> 16) & 1u)) >> 16; return (u16)u; }
DEV float bf2f(u16 h) { return __builtin_bit_cast(float, (u32)h << 16); }
// 3-term split product: a*b ~= ah*bh + ah*bl + al*bh  (al*bl ~ 2^-16 rel, dropped)
DEV f32x4 mfma3(bf16x8 ah, bf16x8 al, bf16x8 bh, bf16x8 bl, f32x4 c) {
  c = __builtin_amdgcn_mfma_f32_16x16x32_bf16(al, bh, c, 0, 0, 0);
  c = __builtin_amdgcn_mfma_f32_16x16x32_bf16(ah, bl, c, 0, 0, 0);
  c = __builtin_amdgcn_mfma_f32_16x16x32_bf16(ah, bh, c, 0, 0, 0);
  return c;
}
DEV void unpack8(uint4 v, u16* d) {
  d[0] = (u16)(v.x & 0xFFFF); d[1] = (u16)(v.x >> 16);
  d[2] = (u16)(v.y & 0xFFFF); d[3] = (u16)(v.y >> 16);
  d[4] = (u16)(v.z & 0xFFFF); d[5] = (u16)(v.z >> 16);
  d[6] = (u16)(v.w & 0xFFFF); d[7] = (u16)(v.w >> 16);
}
DEV uint4 pack8(const u16* d) {
  uint4 v;
  v.x = (u32)d[0] | ((u32)d[1] << 16); v.y = (u32)d[2] | ((u32)d[3] << 16);
  v.z = (u32)d[4] | ((u32)d[5] << 16); v.w = (u32)d[6] | ((u32)d[7] << 16);
  return v;
}

// ---------------- zero stats ----------------
__global__ void k_zero(float* p, int n) {
  int i = blockIdx.x * blockDim.x + threadIdx.x;
  if (i < n) p[i] = 0.f;
}

// ---------------- weight frag preps: layout [((oct*NS + s)*64 + lane)*8 + j] ----------------
__global__ void k_wprep1(const float* __restrict__ w, u16* __restrict__ wh, u16* __restrict__ wl) {
  int idx = blockIdx.x * 256 + threadIdx.x; if (idx >= 8192) return;
  int j = idx & 7, lane = (idx >> 3) & 63, s = (idx >> 9) & 7, oct = idx >> 12;
  int oc = oct * 16 + (lane & 15);
  int kl = ((lane >> 4) << 3) + j;
  int kw = kl >> 2, c = kl & 3, kh = s;
  float v = w[((oc * 4 + c) * 8 + kh) * 8 + kw];
  u16 h = f2bf(v); wh[idx] = h; wl[idx] = f2bf(v - bf2f(h));
}
__global__ void k_wprep2(const float* __restrict__ w, u16* __restrict__ wh, u16* __restrict__ wl) {
  int idx = blockIdx.x * 256 + threadIdx.x; if (idx >= 32768) return;
  int j = idx & 7, lane = (idx >> 3) & 63, s = (idx >> 9) & 15, oct = idx >> 13;
  int oc = oct * 16 + (lane & 15);
  int k = s * 32 + ((lane >> 4) << 3) + j;
  int kh = k >> 7, kw = (k >> 5) & 3, c = k & 31;
  float v = w[((oc * 32 + c) * 4 + kh) * 4 + kw];
  u16 h = f2bf(v); wh[idx] = h; wl[idx] = f2bf(v - bf2f(h));
}
__global__ void k_wprep3(const float* __restrict__ w, u16* __restrict__ wh, u16* __restrict__ wl) {
  int idx = blockIdx.x * 256 + threadIdx.x; if (idx >= 73728) return;
  int j = idx & 7, lane = (idx >> 3) & 63, rest = idx >> 9;
  int s = rest % 18, oct = rest / 18;
  int oc = oct * 16 + (lane & 15);
  int k = s * 32 + ((lane >> 4) << 3) + j;
  int kh = k / 192, r = k - kh * 192;
  int kw = r >> 6, c = r & 63;
  float v = w[((oc * 64 + c) * 3 + kh) * 3 + kw];
  u16 h = f2bf(v); wh[idx] = h; wl[idx] = f2bf(v - bf2f(h));
}
__global__ void k_wprepP(const float* __restrict__ w, u16* __restrict__ wh, u16* __restrict__ wl) {
  int idx = blockIdx.x * 256 + threadIdx.x; if (idx >= 7340032) return;
  int j = idx & 7, lane = (idx >> 3) & 63, rest = idx >> 9;
  int ksg = rest % 896, oct = rest / 896;
  int n = oct * 16 + (lane & 15);
  int ks = ksg * 32 + ((lane >> 4) << 3) + j;
  int kref = (ks & 127) * 224 + (ks >> 7);
  float v = w[(long)n * 28672 + kref];
  u16 h = f2bf(v); wh[idx] = h; wl[idx] = f2bf(v - bf2f(h));
}

// ---------------- conv1 MFMA: x[1024,4,144,160] s4 8x8 -> y1[1024][1365 pix][32 oc] hi/lo
// weights read from global (L2-hot), input in LDS only -> 30 KB LDS, 5 blocks/CU
__global__ __launch_bounds__(256, 4) void k_conv1m(const float* __restrict__ x,
    const u16* __restrict__ wfh, const u16* __restrict__ wfl,
    const float* __restrict__ bias, u16* __restrict__ outh, u16* __restrict__ outl)
{
  __shared__ __align__(16) u16 sin0[7680], sin1[7680];   // [12 rows][160 cols][4 c]
  int ohp = blockIdx.x, b = blockIdx.y, tid = threadIdx.x;
  int row0 = ohp * 8;
  for (int i = tid; i < 3840; i += 256) {
    int cp = i / 1920, jr = i - cp * 1920;
    int r = jr / 160, col = jr - r * 160;
    int grow = row0 + r;
    float v0 = 0.f, v1 = 0.f;
    if (grow < 144) {
      long base = ((long)b * 4 + 2 * cp) * 23040 + (long)grow * 160 + col;
      v0 = x[base]; v1 = x[base + 23040];
    }
    u16 h0 = f2bf(v0), h1 = f2bf(v1);
    u16 l0 = f2bf(v0 - bf2f(h0)), l1 = f2bf(v1 - bf2f(h1));
    ((u32*)sin0)[r * 320 + col * 2 + cp] = (u32)h0 | ((u32)h1 << 16);
    ((u32*)sin1)[r * 320 + col * 2 + cp] = (u32)l0 | ((u32)l1 << 16);
  }
  __syncthreads();
  int w = tid >> 6, lane = tid & 63, g = lane >> 4, ln = lane & 15;
  int ohls[2], owcs[2];
  {
    int j0 = w;          ohls[0] = j0 / 3; owcs[0] = (j0 % 3) * 16 + ln; if (owcs[0] > 38) owcs[0] = 38;
    int j1 = w + 4;      int oh1 = j1 / 3, ow1 = (j1 % 3) * 16 + ln; if (ow1 > 38) ow1 = 38;
    ohls[1] = (j1 < 6) ? oh1 : 0; owcs[1] = (j1 < 6) ? ow1 : 0;
  }
  f32x4 z4 = {0.f, 0.f, 0.f, 0.f};
  f32x4 acc[2][2];
  acc[0][0] = z4; acc[0][1] = z4; acc[1][0] = z4; acc[1][1] = z4;
#pragma unroll
  for (int kh = 0; kh < 8; ++kh) {
    bf16x8 bh0 = *(const bf16x8*)&wfh[kh * 512 + lane * 8];
    bf16x8 bl0 = *(const bf16x8*)&wfl[kh * 512 + lane * 8];
    bf16x8 bh1 = *(const bf16x8*)&wfh[4096 + kh * 512 + lane * 8];
    bf16x8 bl1 = *(const bf16x8*)&wfl[4096 + kh * 512 + lane * 8];
#pragma unroll
    for (int jj = 0; jj < 2; ++jj) {
      if (jj == 1 && w >= 2) continue;
      int off = (4 * ohls[jj] + kh) * 640 + owcs[jj] * 16 + g * 8;
      bf16x8 ah = *(const bf16x8*)&sin0[off];
      bf16x8 al = *(const bf16x8*)&sin1[off];
      acc[jj][0] = mfma3(ah, al, bh0, bl0, acc[jj][0]);
      acc[jj][1] = mfma3(ah, al, bh1, bl1, acc[jj][1]);
    }
  }
#pragma unroll
  for (int jj = 0; jj < 2; ++jj) {
    if (jj == 1 && w >= 2) continue;
    int j = w + jj * 4;
    int ohl = j / 3, owt = j % 3;
    int oh = 2 * ohp + ohl;
    if (oh >= 35) continue;
#pragma unroll
    for (int oct = 0; oct < 2; ++oct) {
      int oc = oct * 16 + ln;
      float bv = bias[oc];
#pragma unroll
      for (int r = 0; r < 4; ++r) {
        int owo = owt * 16 + g * 4 + r;
        if (owo < 39) {
          long oi = ((long)b * 1365 + oh * 39 + owo) * 32 + oc;
          float v = acc[jj][oct][r] + bv;
          u16 hv = f2bf(v);
          outh[oi] = hv; outl[oi] = f2bf(v - bf2f(hv));
        }
      }
    }
  }
}

// ---------------- conv2 MFMA (fused BN1+GELU on staging): raw y1 -> raw y2[1024][288][64]
__global__ __launch_bounds__(256, 3) void k_conv2m(const u16* __restrict__ inh, const u16* __restrict__ inl,
    const u16* __restrict__ wfh, const u16* __restrict__ wfl,
    const float* __restrict__ scale, const float* __restrict__ shift,
    const float* __restrict__ bias, u16* __restrict__ outh, u16* __restrict__ outl)
{
  __shared__ __align__(16) u16 sin0[12480], sin1[12480];  // [10 rows][39 cols][32 c] activated
  __shared__ float sc[32], shf[32];
  int ohq = blockIdx.x, b = blockIdx.y, tid = threadIdx.x;
  if (tid < 32) { sc[tid] = scale[tid]; shf[tid] = shift[tid]; }
  __syncthreads();
  long sb = ((long)b * 1365 + (long)ohq * 8 * 39) * 32;
  const uint4* s0 = (const uint4*)(inh + sb);
  const uint4* s1 = (const uint4*)(inl + sb);
  for (int i = tid; i < 1560; i += 256) {
    uint4 h4 = s0[i], l4 = s1[i];
    u16 hs[8], ls[8], nh[8], nl[8];
    unpack8(h4, hs); unpack8(l4, ls);
    int cb = (i & 3) * 8;
#pragma unroll
    for (int j = 0; j < 8; ++j) {
      float v = bf2f(hs[j]) + bf2f(ls[j]);
      float a = gelu_f(v * sc[cb + j] + shf[cb + j]);
      nh[j] = f2bf(a); nl[j] = f2bf(a - bf2f(nh[j]));
    }
    ((uint4*)sin0)[i] = pack8(nh);
    ((uint4*)sin1)[i] = pack8(nl);
  }
  __syncthreads();
  int w = tid >> 6, lane = tid & 63, g = lane >> 4, ln = lane & 15;
  int rowb[2], colb[2];
#pragma unroll
  for (int jj = 0; jj < 2; ++jj) {
    int pt = jj ? 4 : w;
    int p = pt * 16 + ln; if (p > 71) p = 71;
    int ohl = p / 18, ow = p - 18 * ohl;
    rowb[jj] = 2 * ohl; colb[jj] = 2 * ow;
  }
  for (int oct = 0; oct < 4; ++oct) {
    f32x4 z4 = {0.f, 0.f, 0.f, 0.f};
    f32x4 acc[2]; acc[0] = z4; acc[1] = z4;
#pragma unroll
    for (int s = 0; s < 16; ++s) {
      int kh = s >> 2, kw = s & 3;
      bf16x8 bh = *(const bf16x8*)&wfh[oct * 8192 + s * 512 + lane * 8];
      bf16x8 bl = *(const bf16x8*)&wfl[oct * 8192 + s * 512 + lane * 8];
#pragma unroll
      for (int jj = 0; jj < 2; ++jj) {
        if (jj == 1 && w != 0) continue;
        int off = (rowb[jj] + kh) * 1248 + (colb[jj] + kw) * 32 + g * 8;
        bf16x8 ah = *(const bf16x8*)&sin0[off];
        bf16x8 al = *(const bf16x8*)&sin1[off];
        acc[jj] = mfma3(ah, al, bh, bl, acc[jj]);
      }
    }
    int oc = oct * 16 + ln;
    float bv = bias[oc];
#pragma unroll
    for (int jj = 0; jj < 2; ++jj) {
      if (jj == 1 && w != 0) continue;
      int pt = jj ? 4 : w;
#pragma unroll
      for (int r = 0; r < 4; ++r) {
        int po = pt * 16 + g * 4 + r;
        if (po < 72) {
          long oi = ((long)b * 288 + (long)ohq * 72 + po) * 64 + oc;
          float v = acc[jj][r] + bv;
          u16 hv = f2bf(v);
          outh[oi] = hv; outl[oi] = f2bf(v - bf2f(hv));
        }
      }
    }
  }
}

// ---------------- conv3 MFMA (fused BN2+GELU on staging): raw y2 -> raw y3[1024][224][128]
__global__ __launch_bounds__(256, 3) void k_conv3m(const u16* __restrict__ inh, const u16* __restrict__ inl,
    const u16* __restrict__ wfh, const u16* __restrict__ wfl,
    const float* __restrict__ scale, const float* __restrict__ shift,
    const float* __restrict__ bias, u16* __restrict__ outh, u16* __restrict__ outl)
{
  __shared__ __align__(16) u16 sin0[10368], sin1[10368];  // [9 rows][18 cols][64 c] activated
  __shared__ float sc[64], shf[64];
  int hh = blockIdx.x, b = blockIdx.y, tid = threadIdx.x;
  if (tid < 64) { sc[tid] = scale[tid]; shf[tid] = shift[tid]; }
  __syncthreads();
  long sb = ((long)b * 288 + (long)hh * 126) * 64;
  const uint4* s0 = (const uint4*)(inh + sb);
  const uint4* s1 = (const uint4*)(inl + sb);
  for (int i = tid; i < 1296; i += 256) {
    uint4 h4 = s0[i], l4 = s1[i];
    u16 hs[8], ls[8], nh[8], nl[8];
    unpack8(h4, hs); unpack8(l4, ls);
    int cb = (i & 7) * 8;
#pragma unroll
    for (int j = 0; j < 8; ++j) {
      float v = bf2f(hs[j]) + bf2f(ls[j]);
      float a = gelu_f(v * sc[cb + j] + shf[cb + j]);
      nh[j] = f2bf(a); nl[j] = f2bf(a - bf2f(nh[j]));
    }
    ((uint4*)sin0)[i] = pack8(nh);
    ((uint4*)sin1)[i] = pack8(nl);
  }
  __syncthreads();
  int w = tid >> 6, lane = tid & 63, g = lane >> 4, ln = lane & 15;
  for (int oct = 0; oct < 8; ++oct) {
    f32x4 z4 = {0.f, 0.f, 0.f, 0.f};
    f32x4 acc[2]; acc[0] = z4; acc[1] = z4;
#pragma unroll
    for (int s = 0; s < 18; ++s) {
      const int kh = s / 6, rm = s % 6;
      const int kw = rm >> 1, ch = rm & 1;
      bf16x8 bh = *(const bf16x8*)&wfh[oct * 9216 + s * 512 + lane * 8];
      bf16x8 bl = *(const bf16x8*)&wfl[oct * 9216 + s * 512 + lane * 8];
#pragma unroll
      for (int jj = 0; jj < 2; ++jj) {
        if (jj == 1 && w == 3) continue;
        int ohl = w + jj * 4;
        int off = ((ohl + kh) * 18 + ln + kw) * 64 + ch * 32 + g * 8;
        bf16x8 ah = *(const bf16x8*)&sin0[off];
        bf16x8 al = *(const bf16x8*)&sin1[off];
        acc[jj] = mfma3(ah, al, bh, bl, acc[jj]);
      }
    }
    int oc = oct * 16 + ln;
    float bv = bias[oc];
#pragma unroll
    for (int jj = 0; jj < 2; ++jj) {
      if (jj == 1 && w == 3) continue;
      int ohl = w + jj * 4;
#pragma unroll
      for (int r = 0; r < 4; ++r) {
        int owo = g * 4 + r;
        long oi = ((long)b * 224 + (hh * 7 + ohl) * 16 + owo) * 128 + oc;
        float v = acc[jj][r] + bv;
        u16 hv = f2bf(v);
        outh[oi] = hv; outl[oi] = f2bf(v - bf2f(hv));
      }
    }
  }
}

// ---------------- BN stats over channels-last hi/lo ----------------
__global__ __launch_bounds__(256) void k_bnstat(const u16* __restrict__ h, const u16* __restrict__ l,
    float* __restrict__ sums, int C, long npix)
{
  int half = C >> 1;
  int cp = threadIdx.x % half;
  int rl = threadIdx.x / half;
  int rpi = 256 / half;
  long chunk = (npix + gridDim.x - 1) / gridDim.x;
  long p0 = (long)blockIdx.x * chunk;
  long p1 = p0 + chunk; if (p1 > npix) p1 = npix;
  float s1a = 0.f, s1b = 0.f, s2a = 0.f, s2b = 0.f;
  for (long p = p0 + rl; p < p1; p += rpi) {
    u32 hu = *(const u32*)(h + p * C + cp * 2);
    u32 lu = *(const u32*)(l + p * C + cp * 2);
    float v0 = bf2f((u16)(hu & 0xFFFF)) + bf2f((u16)(lu & 0xFFFF));
    float v1 = bf2f((u16)(hu >> 16)) + bf2f((u16)(lu >> 16));
    s1a += v0; s2a += v0 * v0; s1b += v1; s2b += v1 * v1;
  }
  __shared__ float bs1[128], bs2[128];
  for (int i = threadIdx.x; i < C; i += 256) { bs1[i] = 0.f; bs2[i] = 0.f; }
  __syncthreads();
  atomicAdd(&bs1[2 * cp], s1a); atomicAdd(&bs1[2 * cp + 1], s1b);
  atomicAdd(&bs2[2 * cp], s2a); atomicAdd(&bs2[2 * cp + 1], s2b);
  __syncthreads();
  if (threadIdx.x < C) {
    atomicAdd(&sums[threadIdx.x], bs1[threadIdx.x]);
    atomicAdd(&sums[C + threadIdx.x], bs2[threadIdx.x]);
  }
}

__global__ void k_bn_finalize(const float* __restrict__ sums, const float* __restrict__ g,
    const float* __restrict__ b, float* __restrict__ scale, float* __restrict__ shift,
    int C, float invN)
{
  int c = threadIdx.x;
  if (c < C) {
    float m = sums[c] * invN;
    float var = sums[C + c] * invN - m * m;
    float sc = g[c] * rsqrtf(var + 1e-5f);
    scale[c] = sc;
    shift[c] = b[c] - m * sc;
  }
}

// ---------------- BN apply + GELU, in-place on hi/lo ch-last (y3 only) ----------------
__global__ __launch_bounds__(256) void k_bnapply(u16* __restrict__ h, u16* __restrict__ l,
    const float* __restrict__ scale, const float* __restrict__ shift, int C, long nelem)
{
  __shared__ float sc[128], sh[128];
  for (int i = threadIdx.x; i < C; i += 256) { sc[i] = scale[i]; sh[i] = shift[i]; }
  __syncthreads();
  long i0 = ((long)blockIdx.x * 256 + threadIdx.x) * 4;
  long stride = (long)gridDim.x * 1024;
  for (long i = i0; i < nelem; i += stride) {
    uint2 hu = *(uint2*)(h + i);
    uint2 lu = *(uint2*)(l + i);
    int cb = (int)(i & (long)(C - 1));
    u16 hs[4] = { (u16)(hu.x & 0xFFFF), (u16)(hu.x >> 16), (u16)(hu.y & 0xFFFF), (u16)(hu.y >> 16) };
    u16 ls[4] = { (u16)(lu.x & 0xFFFF), (u16)(lu.x >> 16), (u16)(lu.y & 0xFFFF), (u16)(lu.y >> 16) };
    u16 nh[4], nl[4];
#pragma unroll
    for (int j = 0; j < 4; ++j) {
      float v = bf2f(hs[j]) + bf2f(ls[j]);
      float a = gelu_f(v * sc[cb + j] + sh[cb + j]);
      nh[j] = f2bf(a);
      nl[j] = f2bf(a - bf2f(nh[j]));
    }
    uint2 ho, lo;
    ho.x = (u32)nh[0] | ((u32)nh[1] << 16); ho.y = (u32)nh[2] | ((u32)nh[3] << 16);
    lo.x = (u32)nl[0] | ((u32)nl[1] << 16); lo.y = (u32)nl[2] | ((u32)nl[3] << 16);
    *(uint2*)(h + i) = ho;
    *(uint2*)(l + i) = lo;
  }
}

// ---------------- proj MFMA split-K: [1024 tok x 28672] x [256 x 28672]^T -> part[32][1024][256]
__global__ __launch_bounds__(256, 2) void k_projm(const u16* __restrict__ ah_g, const u16* __restrict__ al_g,
    const u16* __restrict__ bh_g, const u16* __restrict__ bl_g, float* __restrict__ part)
{
  __shared__ __align__(16) u16 Ah[2048], Al[2048];   // [64 tok][32 k]
  __shared__ __align__(16) u16 Bh[8192], Bl[8192];   // [16 oct][512]
  int m0 = blockIdx.x * 64, by = blockIdx.y, tid = threadIdx.x;
  int w = tid >> 6, lane = tid & 63, g = lane >> 4, ln = lane & 15;
  f32x4 z4 = {0.f, 0.f, 0.f, 0.f};
  f32x4 acc[16];
#pragma unroll
  for (int o = 0; o < 16; ++o) acc[o] = z4;
  for (int ks = 0; ks < 28; ++ks) {
    __syncthreads();
    long k0 = ((long)by * 28 + ks) * 32;
#pragma unroll
    for (int ii = 0; ii < 2; ++ii) {
      int i = tid + ii * 256;
      int arr = i >> 8, idx = i & 255, row = idx >> 2, q = idx & 3;
      const u16* src = arr ? al_g : ah_g;
      u16* dst = arr ? Al : Ah;
      ((uint4*)dst)[idx] = *((const uint4*)(src + (long)(m0 + row) * 28672 + k0) + q);
    }
    int ksg = by * 28 + ks;
#pragma unroll
    for (int ii = 0; ii < 8; ++ii) {
      int i = tid + ii * 256;
      int arr = i >> 10, idx = i & 1023, oct = idx >> 6, r2 = idx & 63;
      const u16* src = arr ? bl_g : bh_g;
      u16* dst = arr ? Bl : Bh;
      ((uint4*)dst)[idx] = *((const uint4*)(src + ((long)oct * 896 + ksg) * 512) + r2);
    }
    __syncthreads();
    bf16x8 a_h = *(const bf16x8*)&Ah[(w * 16 + ln) * 32 + g * 8];
    bf16x8 a_l = *(const bf16x8*)&Al[(w * 16 + ln) * 32 + g * 8];
#pragma unroll
    for (int oct = 0; oct < 16; ++oct) {
      bf16x8 bh = *(const bf16x8*)&Bh[oct * 512 + lane * 8];
      bf16x8 bl = *(const bf16x8*)&Bl[oct * 512 + lane * 8];
      acc[oct] = mfma3(a_h, a_l, bh, bl, acc[oct]);
    }
  }
#pragma unroll
  for (int oct = 0; oct < 16; ++oct) {
    int oc = oct * 16 + ln;
#pragma unroll
    for (int r = 0; r < 4; ++r) {
      int tok = m0 + w * 16 + g * 4 + r;
      part[((long)by * 1024 + tok) * 256 + oc] = acc[oct][r];
    }
  }
}

// ---------------- split-K reduce + bias + LN + GELU ----------------
__global__ __launch_bounds__(256) void k_lnred(const float* __restrict__ part,
    const float* __restrict__ pb, const float* __restrict__ g, const float* __restrict__ be,
    float* __restrict__ h)
{
  int b = blockIdx.x, d = threadIdx.x;
  float s = pb[d];
#pragma unroll
  for (int ks = 0; ks < 32; ++ks) s += part[((long)ks * 1024 + b) * 256 + d];
  __shared__ float red[4];
  float t = s;
  for (int o = 32; o; o >>= 1) t += __shfl_xor(t, o);
  if ((d & 63) == 0) red[d >> 6] = t;
  __syncthreads();
  float mean = (red[0] + red[1] + red[2] + red[3]) * (1.f / 256.f);
  __syncthreads();
  float dv = s - mean;
  t = dv * dv;
  for (int o = 32; o; o >>= 1) t += __shfl_xor(t, o);
  if ((d & 63) == 0) red[d >> 6] = t;
  __syncthreads();
  float var = (red[0] + red[1] + red[2] + red[3]) * (1.f / 256.f);
  h[b * 256 + d] = gelu_f(g[d] * dv * rsqrtf(var + 1e-5f) + be[d]);
}

// ---------------- generic fp32 GEMM (experts/shared) ----------------
__global__ __launch_bounds__(256) void k_gemm64(const float* __restrict__ A, int lda,
    const float* __restrict__ B, int ldb, const float* __restrict__ bias,
    float* __restrict__ C, int ldc, int K,
    long aZ, long bZ, long cZ, int biasZ, int act)
{
  int z = blockIdx.z;
  A += (long)z * aZ; B += (long)z * bZ; C += (long)z * cZ;
  int m0 = blockIdx.x * 64, n0 = blockIdx.y * 64, tid = threadIdx.x;
  int tx = tid & 15, ty = tid >> 4;
  __shared__ float As[32][68], Bs[32][68];
  float acc[4][4] = {};
  for (int kt = 0; kt < K; kt += 32) {
#pragma unroll
    for (int s = 0; s < 2; ++s) {
      int t = tid + s * 256;
      int row = t >> 3, kq = (t & 7) * 4;
      float4 av = *(const float4*)(A + (long)(m0 + row) * lda + kt + kq);
      As[kq + 0][row] = av.x; As[kq + 1][row] = av.y; As[kq + 2][row] = av.z; As[kq + 3][row] = av.w;
      float4 bvv = *(const float4*)(B + (long)(n0 + row) * ldb + kt + kq);
      Bs[kq + 0][row] = bvv.x; Bs[kq + 1][row] = bvv.y; Bs[kq + 2][row] = bvv.z; Bs[kq + 3][row] = bvv.w;
    }
    __syncthreads();
#pragma unroll
    for (int kk = 0; kk < 32; ++kk) {
      float4 a4 = *(const float4*)&As[kk][ty * 4];
      float4 b4 = *(const float4*)&Bs[kk][tx * 4];
      acc[0][0] += a4.x * b4.x; acc[0][1] += a4.x * b4.y; acc[0][2] += a4.x * b4.z; acc[0][3] += a4.x * b4.w;
      acc[1][0] += a4.y * b4.x; acc[1][1] += a4.y * b4.y; acc[1][2] += a4.y * b4.z; acc[1][3] += a4.y * b4.w;
      acc[2][0] += a4.z * b4.x; acc[2][1] += a4.z * b4.y; acc[2][2] += a4.z * b4.z; acc[2][3] += a4.z * b4.w;
      acc[3][0] += a4.w * b4.x; acc[3][1] += a4.w * b4.y; acc[3][2] += a4.w * b4.z; acc[3][3] += a4.w * b4.w;
    }
    __syncthreads();
  }
  float bv[4] = {0.f, 0.f, 0.f, 0.f};
  if (bias) {
    const float* bp = bias + (long)z * biasZ + n0 + tx * 4;
    bv[0] = bp[0]; bv[1] = bp[1]; bv[2] = bp[2]; bv[3] = bp[3];
  }
  for (int i = 0; i < 4; ++i) {
    float* op = C + (long)(m0 + ty * 4 + i) * ldc + n0 + tx * 4;
    float4 o;
    o.x = acc[i][0] + bv[0]; o.y = acc[i][1] + bv[1];
    o.z = acc[i][2] + bv[2]; o.w = acc[i][3] + bv[3];
    if (act) { o.x = gelu_f(o.x); o.y = gelu_f(o.y); o.z = gelu_f(o.z); o.w = gelu_f(o.w); }
    *(float4*)op = o;
  }
}

// ---------------- router ----------------
__global__ __launch_bounds__(64) void k_router(const float* __restrict__ h,
    const float* __restrict__ rw, const float* __restrict__ eb,
    float* __restrict__ wts, int* __restrict__ idx,
    float* __restrict__ pm_sum, float* __restrict__ z_sum)
{
  int b = blockIdx.x, lane = threadIdx.x;
  float4 hv = *(const float4*)(h + b * 256 + lane * 4);
  float logit[8];
#pragma unroll
  for (int e = 0; e < 8; ++e) {
    float4 wv = *(const float4*)(rw + e * 256 + lane * 4);
    float p = hv.x * wv.x + hv.y * wv.y + hv.z * wv.z + hv.w * wv.w;
    for (int o = 32; o; o >>= 1) p += __shfl_xor(p, o);
    logit[e] = p + eb[e];
  }
  float mx = logit[0];
#pragma unroll
  for (int e = 1; e < 8; ++e) mx = fmaxf(mx, logit[e]);
  float pr[8]; float se = 0.f;
#pragma unroll
  for (int e = 0; e < 8; ++e) { pr[e] = expf(logit[e] - mx); se += pr[e]; }
  float inv = 1.f / se;
#pragma unroll
  for (int e = 0; e < 8; ++e) pr[e] *= inv;
  int i0 = 0; float v0 = pr[0];
#pragma unroll
  for (int e = 1; e < 8; ++e) if (pr[e] > v0) { v0 = pr[e]; i0 = e; }
  int i1 = -1; float v1 = -1.f;
#pragma unroll
  for (int e = 0; e < 8; ++e) if (e != i0 && pr[e] > v1) { v1 = pr[e]; i1 = e; }
  if (lane == 0) {
    float ssum = v0 + v1 + 1e-8f;
    wts[2 * b] = v0 / ssum; wts[2 * b + 1] = v1 / ssum;
    idx[2 * b] = i0; idx[2 * b + 1] = i1;
    float zz = 0.f;
#pragma unroll
    for (int e = 0; e < 8; ++e) zz += logit[e] * logit[e];
    atomicAdd(z_sum, zz);
  }
  if (lane < 8) atomicAdd(&pm_sum[lane], pr[lane]);
}

// ---------------- combine + 0.5*shared + final LN ----------------
__global__ __launch_bounds__(256) void k_combine_ln(const float* __restrict__ eout,
    const float* __restrict__ sharedB, const float* __restrict__ wts, const int* __restrict__ idx,
    const float* __restrict__ g, const float* __restrict__ bb, float* __restrict__ out)
{
  int b = blockIdx.x, d = threadIdx.x;
  float w0 = wts[2 * b], w1 = wts[2 * b + 1];
  int i0 = idx[2 * b], i1 = idx[2 * b + 1];
  float val = w0 * eout[(long)i0 * 262144 + b * 256 + d]
            + w1 * eout[(long)i1 * 262144 + b * 256 + d]
            + 0.5f * sharedB[b * 256 + d];
  __shared__ float red[4];
  float s = val;
  for (int o = 32; o; o >>= 1) s += __shfl_xor(s, o);
  if ((d & 63) == 0) red[d >> 6] = s;
  __syncthreads();
  float mean = (red[0] + red[1] + red[2] + red[3]) * (1.f / 256.f);
  __syncthreads();
  float dv = val - mean;
  s = dv * dv;
  for (int o = 32; o; o >>= 1) s += __shfl_xor(s, o);
  if ((d & 63) == 0) red[d >> 6] = s;
  __syncthreads();
  float var = (red[0] + red[1] + red[2] + red[3]) * (1.f / 256.f);
  out[b * 256 + d] = g[d] * dv * rsqrtf(var + 1e-5f) + bb[d];
}

// ---------------- aux losses ----------------
__global__ void k_losses(const float* __restrict__ pm_sum, const float* __restrict__ z_sum,
                         float* __restrict__ out)
{
  if (threadIdx.x == 0 && blockIdx.x == 0) {
    float lb = 0.f;
    for (int e = 0; e < 8; ++e) {
      float pm = pm_sum[e] * (1.f / 1024.f);
      float dd = pm - 0.125f;
      lb += dd * dd;
    }
    out[262144] = lb * 8.f;
    out[262145] = z_sum[0] * (1.f / 8192.f) * 0.001f;
  }
}

extern "C" void kernel_launch(void* const* d_in, const int* in_sizes, int n_in,
                              void* d_out, int out_size, void* d_ws, size_t ws_size,
                              hipStream_t stream)
{
  const float* x     = (const float*)d_in[0];
  const float* c1w   = (const float*)d_in[1];
  const float* c1b   = (const float*)d_in[2];
  const float* bn1g  = (const float*)d_in[3];
  const float* bn1b  = (const float*)d_in[4];
  const float* c2w   = (const float*)d_in[5];
  const float* c2b   = (const float*)d_in[6];
  const float* bn2g  = (const float*)d_in[7];
  const float* bn2b  = (const float*)d_in[8];
  const float* c3w   = (const float*)d_in[9];
  const float* c3b   = (const float*)d_in[10];
  const float* bn3g  = (const float*)d_in[11];
  const float* bn3b  = (const float*)d_in[12];
  const float* projw = (const float*)d_in[13];
  const float* projb = (const float*)d_in[14];
  const float* lng   = (const float*)d_in[15];
  const float* lnb   = (const float*)d_in[16];
  const float* rw    = (const float*)d_in[17];
  const float* ebias = (const float*)d_in[18];
  const float* ew1   = (const float*)d_in[19];
  const float* eb1   = (const float*)d_in[20];
  const float* ew2   = (const float*)d_in[21];
  const float* eb2   = (const float*)d_in[22];
  const float* sw1   = (const float*)d_in[23];
  const float* sb1   = (const float*)d_in[24];
  const float* sw2   = (const float*)d_in[25];
  const float* sb2   = (const float*)d_in[26];
  const float* mlng  = (const float*)d_in[27];
  const float* mlnb  = (const float*)d_in[28];
  float* out = (float*)d_out;

  char* W = (char*)d_ws;
  u16* y1h = (u16*)(W + 0);             // 89,456,640
  u16* y1l = (u16*)(W + 89456640L);
  u16* y2h = (u16*)(W + 178913280L);    // 37,748,736
  u16* y2l = (u16*)(W + 216662016L);
  u16* y3h = (u16*)(W + 0);             // alias dead y1 region
  u16* y3l = (u16*)(W + 58720256L);
  u16* wfph = (u16*)(W + 254410752L);   // 14,680,064
  u16* wfpl = (u16*)(W + 269090816L);
  u16* wf1h = (u16*)(W + 283770880L);
  u16* wf1l = (u16*)(W + 283787264L);
  u16* wf2h = (u16*)(W + 283803648L);
  u16* wf2l = (u16*)(W + 283869184L);
  u16* wf3h = (u16*)(W + 283934720L);
  u16* wf3l = (u16*)(W + 284082176L);
  float* stats = (float*)(W + 284229632L);
  float* wtsb  = (float*)(W + 284233728L);
  int*   idxb  = (int*)(W + 284241920L);
  float* hbuf  = (float*)(W + 284250112L);
  float* sh1   = (float*)(W + 285298688L);
  float* shB   = (float*)(W + 286347264L);
  float* part  = (float*)(W + 178913280L);  // alias y2 region (dead by proj time)
  float* hid   = (float*)(W + 178913280L);  // alias after part consumed
  float* eoutB = (float*)(W + 195690496L);

  float* sums1 = stats;        float* scale1 = stats + 512; float* shift1 = stats + 544;
  float* sums2 = stats + 64;   float* scale2 = stats + 576; float* shift2 = stats + 640;
  float* sums3 = stats + 192;  float* scale3 = stats + 704; float* shift3 = stats + 832;
  float* pm    = stats + 448;  float* zsum   = stats + 456;

  dim3 blk(256);
  k_zero<<<dim3(2), blk, 0, stream>>>(stats, 512);
  k_wprep1<<<dim3(32), blk, 0, stream>>>(c1w, wf1h, wf1l);
  k_wprep2<<<dim3(128), blk, 0, stream>>>(c2w, wf2h, wf2l);
  k_wprep3<<<dim3(288), blk, 0, stream>>>(c3w, wf3h, wf3l);
  k_wprepP<<<dim3(28672), blk, 0, stream>>>(projw, wfph, wfpl);

  k_conv1m<<<dim3(18, 1024), blk, 0, stream>>>(x, wf1h, wf1l, c1b, y1h, y1l);
  k_bnstat<<<dim3(512), blk, 0, stream>>>(y1h, y1l, sums1, 32, 1397760L);
  k_bn_finalize<<<1, 32, 0, stream>>>(sums1, bn1g, bn1b, scale1, shift1, 32, 1.f / 1397760.f);

  k_conv2m<<<dim3(4, 1024), blk, 0, stream>>>(y1h, y1l, wf2h, wf2l, scale1, shift1, c2b, y2h, y2l);
  k_bnstat<<<dim3(512), blk, 0, stream>>>(y2h, y2l, sums2, 64, 294912L);
  k_bn_finalize<<<1, 64, 0, stream>>>(sums2, bn2g, bn2b, scale2, shift2, 64, 1.f / 294912.f);

  k_conv3m<<<dim3(2, 1024), blk, 0, stream>>>(y2h, y2l, wf3h, wf3l, scale2, shift2, c3b, y3h, y3l);
  k_bnstat<<<dim3(512), blk, 0, stream>>>(y3h, y3l, sums3, 128, 229376L);
  k_bn_finalize<<<1, 128, 0, stream>>>(sums3, bn3g, bn3b, scale3, shift3, 128, 1.f / 229376.f);
  k_bnapply<<<dim3(2048), blk, 0, stream>>>(y3h, y3l, scale3, shift3, 128, 29360128L);

  k_projm<<<dim3(16, 32), blk, 0, stream>>>(y3h, y3l, wfph, wfpl, part);
  k_lnred<<<dim3(1024), blk, 0, stream>>>(part, projb, lng, lnb, hbuf);

  k_router<<<dim3(1024), dim3(64), 0, stream>>>(hbuf, rw, ebias, wtsb, idxb, pm, zsum);

  k_gemm64<<<dim3(16, 8, 8), blk, 0, stream>>>(hbuf, 256, ew1, 256, eb1,
                                               hid, 512, 256, 0L, 131072L, 524288L, 512, 1);
  k_gemm64<<<dim3(16, 4, 8), blk, 0, stream>>>(hid, 512, ew2, 512, eb2,
                                               eoutB, 256, 512, 524288L, 131072L, 262144L, 256, 0);
  k_gemm64<<<dim3(16, 4, 1), blk, 0, stream>>>(hbuf, 256, sw1, 256, sb1,
                                               sh1, 256, 256, 0L, 0L, 0L, 0, 1);
  k_gemm64<<<dim3(16, 4, 1), blk, 0, stream>>>(sh1, 256, sw2, 256, sb2,
                                               shB, 256, 256, 0L, 0L, 0L, 0, 0);

  k_combine_ln<<<dim3(1024), blk, 0, stream>>>(eoutB, shB, wtsb, idxb, mlng, mlnb, out);
  k_losses<<<1, 64, 0, stream>>>(pm, zsum, out);
}

// Round 6
// 1327.778 us; speedup vs baseline: 19.6730x; 1.1215x over previous
//
#include <hip/hip_runtime.h>
#include <hip/hip_bf16.h>
#include <math.h>

typedef unsigned short u16;
typedef unsigned int u32;
typedef __attribute__((ext_vector_type(8))) short bf16x8;
typedef __attribute__((ext_vector_type(4))) float f32x4;

#define DEV __device__ __forceinline__

DEV float gelu_f(float x) { return 0.5f * x * (1.0f + erff(x * 0.70710678118654752f)); }
DEV u16 f2bf(float f) { u32 u = __builtin_bit_cast(u32, f); u = (u + 0x7FFFu + ((u >> 16) & 1u)) >> 16; return (u16)u; }
DEV float bf2f(u16 h) { return __builtin_bit_cast(float, (u32)h << 16); }
DEV u32 fbits(float f) { return __builtin_bit_cast(u32, f); }
DEV float ubits(u32 u) { return __builtin_bit_cast(float, u); }
// packed format: p = hi_u16 | (lo_u16 << 16), v ~= bf(hi) + bf(lo), trunc split (2^-16)
DEV u32 psplit(float v) {
  u32 u = fbits(v);
  float lo = v - ubits(u & 0xFFFF0000u);
  return (u >> 16) | (fbits(lo) & 0xFFFF0000u);
}
DEV float punp(u32 p) { return ubits(p << 16) + ubits(p & 0xFFFF0000u); }
// 3-term split product: a*b ~= ah*bh + ah*bl + al*bh
DEV f32x4 mfma3(bf16x8 ah, bf16x8 al, bf16x8 bh, bf16x8 bl, f32x4 c) {
  c = __builtin_amdgcn_mfma_f32_16x16x32_bf16(al, bh, c, 0, 0, 0);
  c = __builtin_amdgcn_mfma_f32_16x16x32_bf16(ah, bl, c, 0, 0, 0);
  c = __builtin_amdgcn_mfma_f32_16x16x32_bf16(ah, bh, c, 0, 0, 0);
  return c;
}

// ---------------- zero stats ----------------
__global__ void k_zero(float* p, int n) {
  int i = blockIdx.x * blockDim.x + threadIdx.x;
  if (i < n) p[i] = 0.f;
}

// ---------------- conv weight frag preps: layout [((oct*NS + s)*64 + lane)*8 + j] ----------------
__global__ void k_wprep1(const float* __restrict__ w, u16* __restrict__ wh, u16* __restrict__ wl) {
  int idx = blockIdx.x * 256 + threadIdx.x; if (idx >= 8192) return;
  int j = idx & 7, lane = (idx >> 3) & 63, s = (idx >> 9) & 7, oct = idx >> 12;
  int oc = oct * 16 + (lane & 15);
  int kl = ((lane >> 4) << 3) + j;
  int kw = kl >> 2, c = kl & 3, kh = s;
  float v = w[((oc * 4 + c) * 8 + kh) * 8 + kw];
  u16 h = f2bf(v); wh[idx] = h; wl[idx] = f2bf(v - bf2f(h));
}
__global__ void k_wprep2(const float* __restrict__ w, u16* __restrict__ wh, u16* __restrict__ wl) {
  int idx = blockIdx.x * 256 + threadIdx.x; if (idx >= 32768) return;
  int j = idx & 7, lane = (idx >> 3) & 63, s = (idx >> 9) & 15, oct = idx >> 13;
  int oc = oct * 16 + (lane & 15);
  int k = s * 32 + ((lane >> 4) << 3) + j;
  int kh = k >> 7, kw = (k >> 5) & 3, c = k & 31;
  float v = w[((oc * 32 + c) * 4 + kh) * 4 + kw];
  u16 h = f2bf(v); wh[idx] = h; wl[idx] = f2bf(v - bf2f(h));
}
__global__ void k_wprep3(const float* __restrict__ w, u16* __restrict__ wh, u16* __restrict__ wl) {
  int idx = blockIdx.x * 256 + threadIdx.x; if (idx >= 73728) return;
  int j = idx & 7, lane = (idx >> 3) & 63, rest = idx >> 9;
  int s = rest % 18, oct = rest / 18;
  int oc = oct * 16 + (lane & 15);
  int k = s * 32 + ((lane >> 4) << 3) + j;
  int kh = k / 192, r = k - kh * 192;
  int kw = r >> 6, c = r & 63;
  float v = w[((oc * 64 + c) * 3 + kh) * 3 + kw];
  u16 h = f2bf(v); wh[idx] = h; wl[idx] = f2bf(v - bf2f(h));
}
// proj weight prep, LDS-transpose tiled. Block (q=bx in [0,32), oct=by in [0,16)):
// covers oc3 in [4q,4q+4), all 224 pix, n in oct*16..+15. Coalesced reads.
__global__ __launch_bounds__(256) void k_wprepP(const float* __restrict__ w,
    u16* __restrict__ wh, u16* __restrict__ wl)
{
  __shared__ float tile[16][4][225];
  int q = blockIdx.x, oct = blockIdx.y, tid = threadIdx.x;
  for (int i = tid; i < 3584; i += 256) {
    int n = i / 224, rem = i % 224, e = rem / 56, f4 = rem % 56;
    float4 v = *(const float4*)(w + (long)(oct * 16 + n) * 28672 + (4 * q + e) * 224 + f4 * 4);
    tile[n][e][f4 * 4 + 0] = v.x; tile[n][e][f4 * 4 + 1] = v.y;
    tile[n][e][f4 * 4 + 2] = v.z; tile[n][e][f4 * 4 + 3] = v.w;
  }
  __syncthreads();
  int g = (q >> 1) & 3, j0 = 4 * (q & 1), sgb = q >> 3;
  for (int o = tid; o < 3584; o += 256) {
    int pix = o >> 4, ln = o & 15;
    u16 hs[4], ls[4];
#pragma unroll
    for (int e = 0; e < 4; ++e) {
      float v = tile[ln][e][pix];
      u16 h = f2bf(v); hs[e] = h; ls[e] = f2bf(v - bf2f(h));
    }
    long base = (((long)oct * 896 + pix * 4 + sgb) * 64 + g * 16 + ln) * 8 + j0;
    *(uint2*)(wh + base) = make_uint2((u32)hs[0] | ((u32)hs[1] << 16), (u32)hs[2] | ((u32)hs[3] << 16));
    *(uint2*)(wl + base) = make_uint2((u32)ls[0] | ((u32)ls[1] << 16), (u32)ls[2] | ((u32)ls[3] << 16));
  }
}
// generic plain-bf16 frag prep for expert/shared weights W[Z][N][K]
__global__ void k_wprepG(const float* __restrict__ w, u16* __restrict__ wf,
                         int N, int K, long total)
{
  long idx = (long)blockIdx.x * 256 + threadIdx.x; if (idx >= total) return;
  int j = (int)(idx & 7); int lane = (int)((idx >> 3) & 63); long rest = idx >> 9;
  int kn = K >> 5;
  int s = (int)(rest % kn); long rest2 = rest / kn;
  int noct = N >> 4;
  int oct = (int)(rest2 % noct); int z = (int)(rest2 / noct);
  int n = oct * 16 + (lane & 15);
  int k = s * 32 + ((lane >> 4) << 3) + j;
  wf[idx] = f2bf(w[((long)z * N + n) * K + k]);
}

// ---------------- conv1 MFMA: x[1024,4,144,160] s4 8x8 -> y1p[1024][1365][32] packed
__global__ __launch_bounds__(256, 5) void k_conv1m(const float* __restrict__ x,
    const u16* __restrict__ wfh, const u16* __restrict__ wfl,
    const float* __restrict__ bias, u32* __restrict__ y1p)
{
  __shared__ __align__(16) u16 sin0[7680], sin1[7680];   // [12 rows][160 cols][4 c]
  int ohp = blockIdx.x, b = blockIdx.y, tid = threadIdx.x;
  int row0 = ohp * 8;
  for (int i = tid; i < 960; i += 256) {
    int cp = i / 480, rem = i - cp * 480, r = rem / 40, q = rem - r * 40;
    int grow = row0 + r;
    float4 v0 = make_float4(0.f, 0.f, 0.f, 0.f), v1 = v0;
    if (grow < 144) {
      long base = ((long)b * 4 + 2 * cp) * 23040 + (long)grow * 160 + q * 4;
      v0 = *(const float4*)(x + base);
      v1 = *(const float4*)(x + base + 23040);
    }
    const float* a0 = (const float*)&v0;
    const float* a1 = (const float*)&v1;
#pragma unroll
    for (int m = 0; m < 4; ++m) {
      float f0 = a0[m], f1 = a1[m];
      u32 u0 = fbits(f0), u1 = fbits(f1);
      u32 hh = (u0 >> 16) | (u1 & 0xFFFF0000u);
      float l0 = f0 - ubits(u0 & 0xFFFF0000u);
      float l1 = f1 - ubits(u1 & 0xFFFF0000u);
      u32 ll = (fbits(l0) >> 16) | (fbits(l1) & 0xFFFF0000u);
      int col = q * 4 + m;
      ((u32*)sin0)[r * 320 + col * 2 + cp] = hh;
      ((u32*)sin1)[r * 320 + col * 2 + cp] = ll;
    }
  }
  __syncthreads();
  int w = tid >> 6, lane = tid & 63, g = lane >> 4, ln = lane & 15;
  int ohls[2], owcs[2];
  {
    int j0 = w;          ohls[0] = j0 / 3; owcs[0] = (j0 % 3) * 16 + ln; if (owcs[0] > 38) owcs[0] = 38;
    int j1 = w + 4;      int oh1 = j1 / 3, ow1 = (j1 % 3) * 16 + ln; if (ow1 > 38) ow1 = 38;
    ohls[1] = (j1 < 6) ? oh1 : 0; owcs[1] = (j1 < 6) ? ow1 : 0;
  }
  f32x4 z4 = {0.f, 0.f, 0.f, 0.f};
  f32x4 acc[2][2];
  acc[0][0] = z4; acc[0][1] = z4; acc[1][0] = z4; acc[1][1] = z4;
#pragma unroll
  for (int kh = 0; kh < 8; ++kh) {
    bf16x8 bh0 = *(const bf16x8*)&wfh[kh * 512 + lane * 8];
    bf16x8 bl0 = *(const bf16x8*)&wfl[kh * 512 + lane * 8];
    bf16x8 bh1 = *(const bf16x8*)&wfh[4096 + kh * 512 + lane * 8];
    bf16x8 bl1 = *(const bf16x8*)&wfl[4096 + kh * 512 + lane * 8];
#pragma unroll
    for (int jj = 0; jj < 2; ++jj) {
      if (jj == 1 && w >= 2) continue;
      int off = (4 * ohls[jj] + kh) * 640 + owcs[jj] * 16 + g * 8;
      bf16x8 ah = *(const bf16x8*)&sin0[off];
      bf16x8 al = *(const bf16x8*)&sin1[off];
      acc[jj][0] = mfma3(ah, al, bh0, bl0, acc[jj][0]);
      acc[jj][1] = mfma3(ah, al, bh1, bl1, acc[jj][1]);
    }
  }
#pragma unroll
  for (int jj = 0; jj < 2; ++jj) {
    if (jj == 1 && w >= 2) continue;
    int j = w + jj * 4;
    int ohl = j / 3, owt = j % 3;
    int oh = 2 * ohp + ohl;
    if (oh >= 35) continue;
#pragma unroll
    for (int oct = 0; oct < 2; ++oct) {
      int oc = oct * 16 + ln;
      float bv = bias[oc];
#pragma unroll
      for (int r = 0; r < 4; ++r) {
        int owo = owt * 16 + g * 4 + r;
        if (owo < 39) {
          long oi = ((long)b * 1365 + oh * 39 + owo) * 32 + oc;
          y1p[oi] = psplit(acc[jj][oct][r] + bv);
        }
      }
    }
  }
}

// ---------------- conv2 MFMA (fused BN1+GELU on staging): y1p -> y2p[1024][288][64]
__global__ __launch_bounds__(256, 3) void k_conv2m(const u32* __restrict__ y1p,
    const u16* __restrict__ wfh, const u16* __restrict__ wfl,
    const float* __restrict__ scale, const float* __restrict__ shift,
    const float* __restrict__ bias, u32* __restrict__ y2p)
{
  __shared__ __align__(16) u16 sin0[12480], sin1[12480];  // [10 rows][39 cols][32 c]
  __shared__ float sc[32], shf[32];
  int ohq = blockIdx.x, b = blockIdx.y, tid = threadIdx.x;
  if (tid < 32) { sc[tid] = scale[tid]; shf[tid] = shift[tid]; }
  __syncthreads();
  long sb = ((long)b * 1365 + (long)ohq * 312) * 32;
  const uint4* srcP = (const uint4*)(y1p + sb);
  for (int i = tid; i < 3120; i += 256) {
    uint4 p4 = srcP[i];
    int cb = (i & 7) * 4;
    u32 hw[2], lw[2];
    u32 pe[4] = { p4.x, p4.y, p4.z, p4.w };
#pragma unroll
    for (int half = 0; half < 2; ++half) {
      float va = punp(pe[half * 2 + 0]);
      float vb = punp(pe[half * 2 + 1]);
      float aa = gelu_f(va * sc[cb + half * 2 + 0] + shf[cb + half * 2 + 0]);
      float ab = gelu_f(vb * sc[cb + half * 2 + 1] + shf[cb + half * 2 + 1]);
      u32 ua = fbits(aa), ub = fbits(ab);
      float la = aa - ubits(ua & 0xFFFF0000u);
      float lb = ab - ubits(ub & 0xFFFF0000u);
      hw[half] = (ua >> 16) | (ub & 0xFFFF0000u);
      lw[half] = (fbits(la) >> 16) | (fbits(lb) & 0xFFFF0000u);
    }
    ((uint2*)sin0)[i] = make_uint2(hw[0], hw[1]);
    ((uint2*)sin1)[i] = make_uint2(lw[0], lw[1]);
  }
  __syncthreads();
  int w = tid >> 6, lane = tid & 63, g = lane >> 4, ln = lane & 15;
  int rowb[2], colb[2];
#pragma unroll
  for (int jj = 0; jj < 2; ++jj) {
    int pt = jj ? 4 : w;
    int p = pt * 16 + ln; if (p > 71) p = 71;
    int ohl = p / 18, ow = p - 18 * ohl;
    rowb[jj] = 2 * ohl; colb[jj] = 2 * ow;
  }
  for (int oct = 0; oct < 4; ++oct) {
    f32x4 z4 = {0.f, 0.f, 0.f, 0.f};
    f32x4 acc[2]; acc[0] = z4; acc[1] = z4;
#pragma unroll
    for (int s = 0; s < 16; ++s) {
      int kh = s >> 2, kw = s & 3;
      bf16x8 bh = *(const bf16x8*)&wfh[oct * 8192 + s * 512 + lane * 8];
      bf16x8 bl = *(const bf16x8*)&wfl[oct * 8192 + s * 512 + lane * 8];
#pragma unroll
      for (int jj = 0; jj < 2; ++jj) {
        if (jj == 1 && w != 0) continue;
        int off = (rowb[jj] + kh) * 1248 + (colb[jj] + kw) * 32 + g * 8;
        bf16x8 ah = *(const bf16x8*)&sin0[off];
        bf16x8 al = *(const bf16x8*)&sin1[off];
        acc[jj] = mfma3(ah, al, bh, bl, acc[jj]);
      }
    }
    int oc = oct * 16 + ln;
    float bv = bias[oc];
#pragma unroll
    for (int jj = 0; jj < 2; ++jj) {
      if (jj == 1 && w != 0) continue;
      int pt = jj ? 4 : w;
#pragma unroll
      for (int r = 0; r < 4; ++r) {
        int po = pt * 16 + g * 4 + r;
        if (po < 72) {
          long oi = ((long)b * 288 + (long)ohq * 72 + po) * 64 + oc;
          y2p[oi] = psplit(acc[jj][r] + bv);
        }
      }
    }
  }
}

// ---------------- conv3 MFMA (fused BN2+GELU on staging): y2p -> y3p[1024][224][128]
__global__ __launch_bounds__(256, 3) void k_conv3m(const u32* __restrict__ y2p,
    const u16* __restrict__ wfh, const u16* __restrict__ wfl,
    const float* __restrict__ scale, const float* __restrict__ shift,
    const float* __restrict__ bias, u32* __restrict__ y3p)
{
  __shared__ __align__(16) u16 sin0[10368], sin1[10368];  // [9 rows][18 cols][64 c]
  __shared__ float sc[64], shf[64];
  int hh = blockIdx.x, b = blockIdx.y, tid = threadIdx.x;
  if (tid < 64) { sc[tid] = scale[tid]; shf[tid] = shift[tid]; }
  __syncthreads();
  long sb = ((long)b * 288 + (long)hh * 126) * 64;
  const uint4* srcP = (const uint4*)(y2p + sb);
  for (int i = tid; i < 2592; i += 256) {
    uint4 p4 = srcP[i];
    int cb = (i & 15) * 4;
    u32 hw[2], lw[2];
    u32 pe[4] = { p4.x, p4.y, p4.z, p4.w };
#pragma unroll
    for (int half = 0; half < 2; ++half) {
      float va = punp(pe[half * 2 + 0]);
      float vb = punp(pe[half * 2 + 1]);
      float aa = gelu_f(va * sc[cb + half * 2 + 0] + shf[cb + half * 2 + 0]);
      float ab = gelu_f(vb * sc[cb + half * 2 + 1] + shf[cb + half * 2 + 1]);
      u32 ua = fbits(aa), ub = fbits(ab);
      float la = aa - ubits(ua & 0xFFFF0000u);
      float lb = ab - ubits(ub & 0xFFFF0000u);
      hw[half] = (ua >> 16) | (ub & 0xFFFF0000u);
      lw[half] = (fbits(la) >> 16) | (fbits(lb) & 0xFFFF0000u);
    }
    ((uint2*)sin0)[i] = make_uint2(hw[0], hw[1]);
    ((uint2*)sin1)[i] = make_uint2(lw[0], lw[1]);
  }
  __syncthreads();
  int w = tid >> 6, lane = tid & 63, g = lane >> 4, ln = lane & 15;
  for (int oct = 0; oct < 8; ++oct) {
    f32x4 z4 = {0.f, 0.f, 0.f, 0.f};
    f32x4 acc[2]; acc[0] = z4; acc[1] = z4;
#pragma unroll
    for (int s = 0; s < 18; ++s) {
      const int kh = s / 6, rm = s % 6;
      const int kw = rm >> 1, ch = rm & 1;
      bf16x8 bh = *(const bf16x8*)&wfh[oct * 9216 + s * 512 + lane * 8];
      bf16x8 bl = *(const bf16x8*)&wfl[oct * 9216 + s * 512 + lane * 8];
#pragma unroll
      for (int jj = 0; jj < 2; ++jj) {
        if (jj == 1 && w == 3) continue;
        int ohl = w + jj * 4;
        int off = ((ohl + kh) * 18 + ln + kw) * 64 + ch * 32 + g * 8;
        bf16x8 ah = *(const bf16x8*)&sin0[off];
        bf16x8 al = *(const bf16x8*)&sin1[off];
        acc[jj] = mfma3(ah, al, bh, bl, acc[jj]);
      }
    }
    int oc = oct * 16 + ln;
    float bv = bias[oc];
#pragma unroll
    for (int jj = 0; jj < 2; ++jj) {
      if (jj == 1 && w == 3) continue;
      int ohl = w + jj * 4;
#pragma unroll
      for (int r = 0; r < 4; ++r) {
        int owo = g * 4 + r;
        long oi = ((long)b * 224 + (hh * 7 + ohl) * 16 + owo) * 128 + oc;
        y3p[oi] = psplit(acc[jj][r] + bv);
      }
    }
  }
}

// ---------------- BN stats over packed channels-last ----------------
__global__ __launch_bounds__(256) void k_bnstat(const u32* __restrict__ pk,
    float* __restrict__ sums, int C, long npix)
{
  int half = C >> 1;
  int cp = threadIdx.x % half;
  int rl = threadIdx.x / half;
  int rpi = 256 / half;
  long chunk = (npix + gridDim.x - 1) / gridDim.x;
  long p0 = (long)blockIdx.x * chunk;
  long p1 = p0 + chunk; if (p1 > npix) p1 = npix;
  float s1a = 0.f, s1b = 0.f, s2a = 0.f, s2b = 0.f;
  for (long p = p0 + rl; p < p1; p += rpi) {
    uint2 pu = *(const uint2*)(pk + p * C + cp * 2);
    float v0 = punp(pu.x);
    float v1 = punp(pu.y);
    s1a += v0; s2a += v0 * v0; s1b += v1; s2b += v1 * v1;
  }
  __shared__ float bs1[128], bs2[128];
  for (int i = threadIdx.x; i < C; i += 256) { bs1[i] = 0.f; bs2[i] = 0.f; }
  __syncthreads();
  atomicAdd(&bs1[2 * cp], s1a); atomicAdd(&bs1[2 * cp + 1], s1b);
  atomicAdd(&bs2[2 * cp], s2a); atomicAdd(&bs2[2 * cp + 1], s2b);
  __syncthreads();
  if (threadIdx.x < C) {
    atomicAdd(&sums[threadIdx.x], bs1[threadIdx.x]);
    atomicAdd(&sums[C + threadIdx.x], bs2[threadIdx.x]);
  }
}

__global__ void k_bn_finalize(const float* __restrict__ sums, const float* __restrict__ g,
    const float* __restrict__ b, float* __restrict__ scale, float* __restrict__ shift,
    int C, float invN)
{
  int c = threadIdx.x;
  if (c < C) {
    float m = sums[c] * invN;
    float var = sums[C + c] * invN - m * m;
    float sc = g[c] * rsqrtf(var + 1e-5f);
    scale[c] = sc;
    shift[c] = b[c] - m * sc;
  }
}

// ---------------- BN apply + GELU in-place on packed (y3) ----------------
__global__ __launch_bounds__(256) void k_bnapplyP(u32* __restrict__ pk,
    const float* __restrict__ scale, const float* __restrict__ shift, int C, long nelem)
{
  __shared__ float sc[128], sh[128];
  for (int i = threadIdx.x; i < C; i += 256) { sc[i] = scale[i]; sh[i] = shift[i]; }
  __syncthreads();
  long i0 = ((long)blockIdx.x * 256 + threadIdx.x) * 4;
  long stride = (long)gridDim.x * 1024;
  for (long i = i0; i < nelem; i += stride) {
    uint4 v4 = *(uint4*)(pk + i);
    int cb = (int)(i & (long)(C - 1));
    u32 src[4] = { v4.x, v4.y, v4.z, v4.w };
    u32 r[4];
#pragma unroll
    for (int j = 0; j < 4; ++j) {
      float v = punp(src[j]);
      float a = gelu_f(v * sc[cb + j] + sh[cb + j]);
      r[j] = psplit(a);
    }
    *(uint4*)(pk + i) = make_uint4(r[0], r[1], r[2], r[3]);
  }
}

// ---------------- proj MFMA split-K: y3p tokens x wfp -> part[32][1024][256]
__global__ __launch_bounds__(256, 2) void k_projm(const u32* __restrict__ y3p,
    const u16* __restrict__ bh_g, const u16* __restrict__ bl_g, float* __restrict__ part)
{
  __shared__ __align__(16) u16 Ah[2048], Al[2048];   // [64 tok][32 k]
  __shared__ __align__(16) u16 Bh[8192], Bl[8192];   // [16 oct][512]
  int m0 = blockIdx.x * 64, by = blockIdx.y, tid = threadIdx.x;
  int w = tid >> 6, lane = tid & 63, g = lane >> 4, ln = lane & 15;
  f32x4 z4 = {0.f, 0.f, 0.f, 0.f};
  f32x4 acc[16];
#pragma unroll
  for (int o = 0; o < 16; ++o) acc[o] = z4;
  for (int ks = 0; ks < 28; ++ks) {
    __syncthreads();
    long k0 = ((long)by * 28 + ks) * 32;
    {
      // A: 512 uint4 of packed -> unpack to Ah/Al
      for (int ii = 0; ii < 2; ++ii) {
        int i = tid + ii * 256;
        int row = i >> 3, q = i & 7;
        uint4 p4 = *((const uint4*)(y3p + (long)(m0 + row) * 28672 + k0) + q);
        u32 h01 = (p4.x & 0xFFFFu) | (p4.y << 16);
        u32 l01 = (p4.x >> 16) | (p4.y & 0xFFFF0000u);
        u32 h23 = (p4.z & 0xFFFFu) | (p4.w << 16);
        u32 l23 = (p4.z >> 16) | (p4.w & 0xFFFF0000u);
        ((uint2*)Ah)[i] = make_uint2(h01, h23);
        ((uint2*)Al)[i] = make_uint2(l01, l23);
      }
    }
    int ksg = by * 28 + ks;
#pragma unroll
    for (int ii = 0; ii < 8; ++ii) {
      int i = tid + ii * 256;
      int arr = i >> 10, idx = i & 1023, oct = idx >> 6, r2 = idx & 63;
      const u16* src = arr ? bl_g : bh_g;
      u16* dst = arr ? Bl : Bh;
      ((uint4*)dst)[idx] = *((const uint4*)(src + ((long)oct * 896 + ksg) * 512) + r2);
    }
    __syncthreads();
    bf16x8 a_h = *(const bf16x8*)&Ah[(w * 16 + ln) * 32 + g * 8];
    bf16x8 a_l = *(const bf16x8*)&Al[(w * 16 + ln) * 32 + g * 8];
#pragma unroll
    for (int oct = 0; oct < 16; ++oct) {
      bf16x8 bh = *(const bf16x8*)&Bh[oct * 512 + lane * 8];
      bf16x8 bl = *(const bf16x8*)&Bl[oct * 512 + lane * 8];
      acc[oct] = mfma3(a_h, a_l, bh, bl, acc[oct]);
    }
  }
#pragma unroll
  for (int oct = 0; oct < 16; ++oct) {
    int oc = oct * 16 + ln;
#pragma unroll
    for (int r = 0; r < 4; ++r) {
      int tok = m0 + w * 16 + g * 4 + r;
      part[((long)by * 1024 + tok) * 256 + oc] = acc[oct][r];
    }
  }
}

// ---------------- split-K reduce + bias + LN + GELU (writes f32 h and bf16 h) ----------------
__global__ __launch_bounds__(256) void k_lnred(const float* __restrict__ part,
    const float* __restrict__ pb, const float* __restrict__ g, const float* __restrict__ be,
    float* __restrict__ h, u16* __restrict__ hb)
{
  int b = blockIdx.x, d = threadIdx.x;
  float s = pb[d];
#pragma unroll
  for (int ks = 0; ks < 32; ++ks) s += part[((long)ks * 1024 + b) * 256 + d];
  __shared__ float red[4];
  float t = s;
  for (int o = 32; o; o >>= 1) t += __shfl_xor(t, o);
  if ((d & 63) == 0) red[d >> 6] = t;
  __syncthreads();
  float mean = (red[0] + red[1] + red[2] + red[3]) * (1.f / 256.f);
  __syncthreads();
  float dv = s - mean;
  t = dv * dv;
  for (int o = 32; o; o >>= 1) t += __shfl_xor(t, o);
  if ((d & 63) == 0) red[d >> 6] = t;
  __syncthreads();
  float var = (red[0] + red[1] + red[2] + red[3]) * (1.f / 256.f);
  float hv = gelu_f(g[d] * dv * rsqrtf(var + 1e-5f) + be[d]);
  h[b * 256 + d] = hv;
  hb[b * 256 + d] = f2bf(hv);
}

// ---------------- generic plain-bf16 MFMA GEMM: C[z][M][N] = A[z][M][K] @ Bfrag + bias
__global__ __launch_bounds__(256, 2) void k_gemmb(const u16* __restrict__ A, long aZ, int K,
    const u16* __restrict__ Bf, int noct_tot,
    const float* __restrict__ bias, int biasZ,
    void* __restrict__ C, long cZ, int ldc, int outbf, int act)
{
  __shared__ __align__(16) u16 As[2048];
  __shared__ __align__(16) u16 Bs[8192];
  int m0 = blockIdx.x * 64, nb = blockIdx.y, z = blockIdx.z, tid = threadIdx.x;
  int w = tid >> 6, lane = tid & 63, g = lane >> 4, ln = lane & 15;
  const u16* Az = A + (long)z * aZ;
  int kn = K >> 5;
  f32x4 z4 = {0.f, 0.f, 0.f, 0.f};
  f32x4 acc[16];
#pragma unroll
  for (int o = 0; o < 16; ++o) acc[o] = z4;
  for (int ks = 0; ks < kn; ++ks) {
    __syncthreads();
    {
      int row = tid >> 2, q = tid & 3;
      ((uint4*)As)[tid] = *((const uint4*)(Az + (long)(m0 + row) * K + ks * 32) + q);
    }
#pragma unroll
    for (int ii = 0; ii < 4; ++ii) {
      int i = tid + ii * 256;
      int oct = i >> 6, r2 = i & 63;
      const u16* src = Bf + (((long)z * noct_tot + nb * 16 + oct) * kn + ks) * 512;
      ((uint4*)Bs)[i] = ((const uint4*)src)[r2];
    }
    __syncthreads();
    bf16x8 a = *(const bf16x8*)&As[(w * 16 + ln) * 32 + g * 8];
#pragma unroll
    for (int oct = 0; oct < 16; ++oct) {
      bf16x8 bb = *(const bf16x8*)&Bs[oct * 512 + lane * 8];
      acc[oct] = __builtin_amdgcn_mfma_f32_16x16x32_bf16(a, bb, acc[oct], 0, 0, 0);
    }
  }
#pragma unroll
  for (int oct = 0; oct < 16; ++oct) {
    int n = nb * 256 + oct * 16 + ln;
    float bv = bias[z * biasZ + n];
#pragma unroll
    for (int r = 0; r < 4; ++r) {
      int tok = m0 + w * 16 + g * 4 + r;
      float v = acc[oct][r] + bv;
      if (act) v = gelu_f(v);
      long off = (long)z * cZ + (long)tok * ldc + n;
      if (outbf) ((u16*)C)[off] = f2bf(v);
      else ((float*)C)[off] = v;
    }
  }
}

// ---------------- router ----------------
__global__ __launch_bounds__(64) void k_router(const float* __restrict__ h,
    const float* __restrict__ rw, const float* __restrict__ eb,
    float* __restrict__ wts, int* __restrict__ idx,
    float* __restrict__ pm_sum, float* __restrict__ z_sum)
{
  int b = blockIdx.x, lane = threadIdx.x;
  float4 hv = *(const float4*)(h + b * 256 + lane * 4);
  float logit[8];
#pragma unroll
  for (int e = 0; e < 8; ++e) {
    float4 wv = *(const float4*)(rw + e * 256 + lane * 4);
    float p = hv.x * wv.x + hv.y * wv.y + hv.z * wv.z + hv.w * wv.w;
    for (int o = 32; o; o >>= 1) p += __shfl_xor(p, o);
    logit[e] = p + eb[e];
  }
  float mx = logit[0];
#pragma unroll
  for (int e = 1; e < 8; ++e) mx = fmaxf(mx, logit[e]);
  float pr[8]; float se = 0.f;
#pragma unroll
  for (int e = 0; e < 8; ++e) { pr[e] = expf(logit[e] - mx); se += pr[e]; }
  float inv = 1.f / se;
#pragma unroll
  for (int e = 0; e < 8; ++e) pr[e] *= inv;
  int i0 = 0; float v0 = pr[0];
#pragma unroll
  for (int e = 1; e < 8; ++e) if (pr[e] > v0) { v0 = pr[e]; i0 = e; }
  int i1 = -1; float v1 = -1.f;
#pragma unroll
  for (int e = 0; e < 8; ++e) if (e != i0 && pr[e] > v1) { v1 = pr[e]; i1 = e; }
  if (lane == 0) {
    float ssum = v0 + v1 + 1e-8f;
    wts[2 * b] = v0 / ssum; wts[2 * b + 1] = v1 / ssum;
    idx[2 * b] = i0; idx[2 * b + 1] = i1;
    float zz = 0.f;
#pragma unroll
    for (int e = 0; e < 8; ++e) zz += logit[e] * logit[e];
    atomicAdd(z_sum, zz);
  }
  if (lane < 8) atomicAdd(&pm_sum[lane], pr[lane]);
}

// ---------------- combine + 0.5*shared + final LN ----------------
__global__ __launch_bounds__(256) void k_combine_ln(const float* __restrict__ eout,
    const float* __restrict__ sharedB, const float* __restrict__ wts, const int* __restrict__ idx,
    const float* __restrict__ g, const float* __restrict__ bb, float* __restrict__ out)
{
  int b = blockIdx.x, d = threadIdx.x;
  float w0 = wts[2 * b], w1 = wts[2 * b + 1];
  int i0 = idx[2 * b], i1 = idx[2 * b + 1];
  float val = w0 * eout[(long)i0 * 262144 + b * 256 + d]
            + w1 * eout[(long)i1 * 262144 + b * 256 + d]
            + 0.5f * sharedB[b * 256 + d];
  __shared__ float red[4];
  float s = val;
  for (int o = 32; o; o >>= 1) s += __shfl_xor(s, o);
  if ((d & 63) == 0) red[d >> 6] = s;
  __syncthreads();
  float mean = (red[0] + red[1] + red[2] + red[3]) * (1.f / 256.f);
  __syncthreads();
  float dv = val - mean;
  s = dv * dv;
  for (int o = 32; o; o >>= 1) s += __shfl_xor(s, o);
  if ((d & 63) == 0) red[d >> 6] = s;
  __syncthreads();
  float var = (red[0] + red[1] + red[2] + red[3]) * (1.f / 256.f);
  out[b * 256 + d] = g[d] * dv * rsqrtf(var + 1e-5f) + bb[d];
}

// ---------------- aux losses ----------------
__global__ void k_losses(const float* __restrict__ pm_sum, const float* __restrict__ z_sum,
                         float* __restrict__ out)
{
  if (threadIdx.x == 0 && blockIdx.x == 0) {
    float lb = 0.f;
    for (int e = 0; e < 8; ++e) {
      float pm = pm_sum[e] * (1.f / 1024.f);
      float dd = pm - 0.125f;
      lb += dd * dd;
    }
    out[262144] = lb * 8.f;
    out[262145] = z_sum[0] * (1.f / 8192.f) * 0.001f;
  }
}

extern "C" void kernel_launch(void* const* d_in, const int* in_sizes, int n_in,
                              void* d_out, int out_size, void* d_ws, size_t ws_size,
                              hipStream_t stream)
{
  const float* x     = (const float*)d_in[0];
  const float* c1w   = (const float*)d_in[1];
  const float* c1b   = (const float*)d_in[2];
  const float* bn1g  = (const float*)d_in[3];
  const float* bn1b  = (const float*)d_in[4];
  const float* c2w   = (const float*)d_in[5];
  const float* c2b   = (const float*)d_in[6];
  const float* bn2g  = (const float*)d_in[7];
  const float* bn2b  = (const float*)d_in[8];
  const float* c3w   = (const float*)d_in[9];
  const float* c3b   = (const float*)d_in[10];
  const float* bn3g  = (const float*)d_in[11];
  const float* bn3b  = (const float*)d_in[12];
  const float* projw = (const float*)d_in[13];
  const float* projb = (const float*)d_in[14];
  const float* lng   = (const float*)d_in[15];
  const float* lnb   = (const float*)d_in[16];
  const float* rw    = (const float*)d_in[17];
  const float* ebias = (const float*)d_in[18];
  const float* ew1   = (const float*)d_in[19];
  const float* eb1   = (const float*)d_in[20];
  const float* ew2   = (const float*)d_in[21];
  const float* eb2   = (const float*)d_in[22];
  const float* sw1   = (const float*)d_in[23];
  const float* sb1   = (const float*)d_in[24];
  const float* sw2   = (const float*)d_in[25];
  const float* sb2   = (const float*)d_in[26];
  const float* mlng  = (const float*)d_in[27];
  const float* mlnb  = (const float*)d_in[28];
  float* out = (float*)d_out;

  char* W = (char*)d_ws;
  u32* y1p = (u32*)(W + 0);              // 178,913,280 B
  u32* y2p = (u32*)(W + 178913280L);     // 75,497,472 B
  u32* y3p = (u32*)(W + 0);              // 117,440,512 B (alias dead y1)
  u16* wfph = (u16*)(W + 254410752L);
  u16* wfpl = (u16*)(W + 269090816L);
  u16* wf1h = (u16*)(W + 283770880L);
  u16* wf1l = (u16*)(W + 283787264L);
  u16* wf2h = (u16*)(W + 283803648L);
  u16* wf2l = (u16*)(W + 283869184L);
  u16* wf3h = (u16*)(W + 283934720L);
  u16* wf3l = (u16*)(W + 284082176L);
  float* stats = (float*)(W + 284229632L);
  float* wtsb  = (float*)(W + 284233728L);
  int*   idxb  = (int*)(W + 284241920L);
  float* hbuf  = (float*)(W + 284250112L);
  float* shB   = (float*)(W + 286347264L);
  // tail region inside the y2p span — all used only after conv3m completes
  float* part  = (float*)(W + 178913280L);  // 33,554,432 B
  u16* hid     = (u16*)(W + 212467712L);    // 8,388,608 B
  u16* ewf1    = (u16*)(W + 220856320L);    // 2,097,152 B
  u16* ewf2    = (u16*)(W + 222953472L);    // 2,097,152 B
  u16* swf1    = (u16*)(W + 225050624L);    // 131,072 B
  u16* swf2    = (u16*)(W + 225181696L);    // 131,072 B
  float* eoutB = (float*)(W + 225312768L);  // 8,388,608 B
  u16* hbufb   = (u16*)(W + 233701376L);    // 524,288 B
  u16* sh1b    = (u16*)(W + 234225664L);    // 524,288 B

  float* sums1 = stats;        float* scale1 = stats + 512; float* shift1 = stats + 544;
  float* sums2 = stats + 64;   float* scale2 = stats + 576; float* shift2 = stats + 640;
  float* sums3 = stats + 192;  float* scale3 = stats + 704; float* shift3 = stats + 832;
  float* pm    = stats + 448;  float* zsum   = stats + 456;

  dim3 blk(256);
  k_zero<<<dim3(2), blk, 0, stream>>>(stats, 512);
  k_wprep1<<<dim3(32), blk, 0, stream>>>(c1w, wf1h, wf1l);
  k_wprep2<<<dim3(128), blk, 0, stream>>>(c2w, wf2h, wf2l);
  k_wprep3<<<dim3(288), blk, 0, stream>>>(c3w, wf3h, wf3l);
  k_wprepP<<<dim3(32, 16), blk, 0, stream>>>(projw, wfph, wfpl);

  k_conv1m<<<dim3(18, 1024), blk, 0, stream>>>(x, wf1h, wf1l, c1b, y1p);
  k_bnstat<<<dim3(512), blk, 0, stream>>>(y1p, sums1, 32, 1397760L);
  k_bn_finalize<<<1, 32, 0, stream>>>(sums1, bn1g, bn1b, scale1, shift1, 32, 1.f / 1397760.f);

  k_conv2m<<<dim3(4, 1024), blk, 0, stream>>>(y1p, wf2h, wf2l, scale1, shift1, c2b, y2p);
  k_bnstat<<<dim3(512), blk, 0, stream>>>(y2p, sums2, 64, 294912L);
  k_bn_finalize<<<1, 64, 0, stream>>>(sums2, bn2g, bn2b, scale2, shift2, 64, 1.f / 294912.f);

  k_conv3m<<<dim3(2, 1024), blk, 0, stream>>>(y2p, wf3h, wf3l, scale2, shift2, c3b, y3p);
  k_bnstat<<<dim3(512), blk, 0, stream>>>(y3p, sums3, 128, 229376L);
  k_bn_finalize<<<1, 128, 0, stream>>>(sums3, bn3g, bn3b, scale3, shift3, 128, 1.f / 229376.f);
  k_bnapplyP<<<dim3(2048), blk, 0, stream>>>(y3p, scale3, shift3, 128, 29360128L);

  // expert/shared weight preps (y2p region is dead now)
  k_wprepG<<<dim3(4096), blk, 0, stream>>>(ew1, ewf1, 512, 256, 1048576L);
  k_wprepG<<<dim3(4096), blk, 0, stream>>>(ew2, ewf2, 256, 512, 1048576L);
  k_wprepG<<<dim3(256), blk, 0, stream>>>(sw1, swf1, 256, 256, 65536L);
  k_wprepG<<<dim3(256), blk, 0, stream>>>(sw2, swf2, 256, 256, 65536L);

  k_projm<<<dim3(16, 32), blk, 0, stream>>>(y3p, wfph, wfpl, part);
  k_lnred<<<dim3(1024), blk, 0, stream>>>(part, projb, lng, lnb, hbuf, hbufb);

  k_router<<<dim3(1024), dim3(64), 0, stream>>>(hbuf, rw, ebias, wtsb, idxb, pm, zsum);

  // experts (dense) + shared, plain bf16 MFMA
  k_gemmb<<<dim3(16, 2, 8), blk, 0, stream>>>(hbufb, 0L, 256, ewf1, 32, eb1, 512,
                                              (void*)hid, 524288L, 512, 1, 1);
  k_gemmb<<<dim3(16, 1, 8), blk, 0, stream>>>(hid, 524288L, 512, ewf2, 16, eb2, 256,
                                              (void*)eoutB, 262144L, 256, 0, 0);
  k_gemmb<<<dim3(16, 1, 1), blk, 0, stream>>>(hbufb, 0L, 256, swf1, 16, sb1, 0,
                                              (void*)sh1b, 0L, 256, 1, 1);
  k_gemmb<<<dim3(16, 1, 1), blk, 0, stream>>>(sh1b, 0L, 256, swf2, 16, sb2, 0,
                                              (void*)shB, 0L, 256, 0, 0);

  k_combine_ln<<<dim3(1024), blk, 0, stream>>>(eoutB, shB, wtsb, idxb, mlng, mlnb, out);
  k_losses<<<1, 64, 0, stream>>>(pm, zsum, out);
}